// Round 11
// baseline (846.582 us; speedup 1.0000x reference)
//
#include <hip/hip_runtime.h>
#include <cstdint>
#include <cstddef>

#define D 128
#define H 8
#define NSRC 200000
#define NE0  100000
#define NE1  50000
#define E0N  1000000
#define E1N  500000
#define NT   (NE0 + NE1)
#define ET   (E0N + E1N)

typedef unsigned short u16;
typedef __attribute__((ext_vector_type(8))) short short8;
typedef __attribute__((ext_vector_type(4))) float f32x4;
typedef __attribute__((ext_vector_type(2))) float f32x2;

// ---------- bf16 helpers ----------
__device__ __forceinline__ u16 f2bf(float f) {
  unsigned u = __float_as_uint(f);
  unsigned r = (u + 0x7fffu + ((u >> 16) & 1u)) >> 16;  // RNE
  return (u16)r;
}
__device__ __forceinline__ float bf2f(u16 u) {
  return __uint_as_float(((unsigned)u) << 16);
}
// unpack 2 packed bf16 (low = even dim) -> f32x2
__device__ __forceinline__ f32x2 unpk(unsigned u) {
  f32x2 r;
  r.x = __uint_as_float(u << 16);
  r.y = __uint_as_float(u & 0xffff0000u);
  return r;
}
// bf16 pair dot with f32 accumulate: d = a.lo*b.lo + a.hi*b.hi + c
__device__ __forceinline__ float dot2bf(unsigned a, unsigned b, float c) {
  float d;
  asm("v_dot2_f32_bf16 %0, %1, %2, %3" : "=v"(d) : "v"(a), "v"(b), "v"(c));
  return d;
}
__device__ __forceinline__ f32x2 fma2(f32x2 a, f32x2 b, f32x2 c) {
  return __builtin_elementwise_fma(a, b, c);
}

// ---------- mega-prep: x cast + weight transpose + emb GEMMs + zero-fill ----------
// block roles: [0,BC) cast | [BC,BC+64) weights | +4 embs | +BZ zero offs | +1 zero bn
#define BC 25000            // (NSRC*D/4)/256
#define BZ 147              // ceil((NT+1)/1024)
static_assert((size_t)BZ * 1024 >= NT + 1, "offs zero-fill must cover NT+1 entries");
__global__ __launch_bounds__(256) void prep_all(
    const float* __restrict__ x, u16* __restrict__ xb,
    const float* w0, const float* w1, const float* w2, const float* w3,
    const float* w4, const float* w5, const float* w6, const float* w7,
    u16* __restrict__ wt,
    const float* __restrict__ embA, const float* __restrict__ embB,
    const float* __restrict__ We0, const float* __restrict__ We1,
    float* __restrict__ kv,
    int* __restrict__ offs, float* __restrict__ bnsums) {
  int b = blockIdx.x;
  if (b < BC) {
    int i = b * 256 + threadIdx.x;
    float4 a = ((const float4*)x)[i];
    ushort4 o;
    o.x = f2bf(a.x); o.y = f2bf(a.y); o.z = f2bf(a.z); o.w = f2bf(a.w);
    ((ushort4*)xb)[i] = o;
  } else if (b < BC + 64) {
    int bb = b - BC;
    const float* wsrc[8] = {w0, w1, w2, w3, w4, w5, w6, w7};
    int mat = bb >> 3;
    int blk = bb & 7;
    const float* W = wsrc[mat];
    // fold 1/sqrt(d)=0.25 into Wq (mats 2 and 6) so Q comes out pre-scaled
    float sc = ((mat & 3) == 2) ? 0.25f : 1.0f;
    u16* out = wt + mat * 16384;
    for (int i = blk * 2048 + threadIdx.x; i < (blk + 1) * 2048; i += 256) {
      int n = i >> 7, k = i & 127;
      out[i] = f2bf(W[k * 128 + n] * sc);
    }
  } else if (b < BC + 68) {
    int bb = b - BC - 64;
    int mat = bb >> 1;
    int t = (bb & 1) * 256 + threadIdx.x;
    const float* We = mat ? We1 : We0;
    float* keOut = kv + mat * 1024;
    float* veOut = keOut + 512;
    int r = t >> 7, c = t & 127;
    float s0 = 0.f, s1 = 0.f;
    for (int k = 0; k < 128; ++k) {
      float w = We[k * 128 + c];
      s0 += embA[r * 128 + k] * w;
      s1 += embB[r * 128 + k] * w;
    }
    keOut[t] = s0;
    veOut[t] = s1;
  } else if (b < BC + 68 + BZ) {
    int base = (b - BC - 68) * 1024 + threadIdx.x * 4;
#pragma unroll
    for (int i = 0; i < 4; ++i)
      if (base + i < NT + 1) offs[base + i] = 0;
  } else {
    bnsums[threadIdx.x] = 0.f;  // 256 floats = bnsum|bnsq
  }
}

// ---------- quad-output MFMA GEMM, persistent weights-in-LDS (R11) ----------
// R10 accounting: ~480us is in sub-92us kernels; gemm is the largest likely
// member. Structural waste: all 2344 blocks re-staged the SAME 64KB weight
// pair (150MB redundant L2 reads + per-block barrier), and each block's
// A->MFMA->store chain ran once, unamortized. Fix: PERSISTENT blocks.
// grid=512 (2/CU, LDS-capped), split into KV-group [0,gKV) and QS-group
// [gKV,512). Each block stages its weight pair ONCE, then loops over its
// row-tiles with NO barrier in the loop (weights read-only; waves
// independent -> tile t+1 A-loads overlap tile t MFMA/stores via TLP).
__global__ __launch_bounds__(512, 4) void gemm_quad(
    const u16* __restrict__ A,
    const u16* __restrict__ WtK, const u16* __restrict__ WtV,
    u16* __restrict__ CKV, int NA, int nKV,
    const u16* __restrict__ WtQ, const u16* __restrict__ WtS,
    u16* __restrict__ CQ, u16* __restrict__ CS, int NB, int gKV) {
  int bb = blockIdx.x;
  bool ilv = (bb < gKV);
  const u16* Wt0 = ilv ? WtK : WtQ;
  const u16* Wt1 = ilv ? WtV : WtS;
  int N       = ilv ? NA : NB;
  int ntiles  = ilv ? nKV : ((NB + 127) >> 7);
  int tstart  = ilv ? bb : (bb - gKV);
  int gsize   = ilv ? gKV : (gridDim.x - gKV);

  int tid = threadIdx.x;
  int w = tid >> 6, lane = tid & 63;
  int g = w >> 1;          // row group within tile: rows [g*32, g*32+32)
  int h = w & 1;           // feature half: features [h*64, h*64+64)
  int lrow = lane & 15, q = lane >> 4;

  __shared__ u16 Wls[2 * 128 * 128];  // 64 KB: both mats, chunk-XOR swizzled

  // stage weights ONCE per block (L2-hot: same 64KB for all blocks of a kind)
  {
    uint4 wv[8];
#pragma unroll
    for (int i = 0; i < 8; ++i) {
      int m = i * 512 + tid;                       // 4096 x 16B chunks
      const u16* Wsrc = (m >> 11) ? Wt1 : Wt0;
      wv[i] = *(const uint4*)(Wsrc + (size_t)(m & 2047) * 8);
    }
    // LDS write (chunk-XOR swizzle: LDS(row,c) = W(row, c ^ (row&15)))
#pragma unroll
    for (int i = 0; i < 8; ++i) {
      int m = i * 512 + tid;
      int row = (m & 2047) >> 4, c = m & 15;
      *(uint4*)(Wls + (m >> 11) * 16384 + row * 128 + (c ^ (row & 15)) * 8) = wv[i];
    }
  }
  __syncthreads();

  const u16* W0 = Wls + (h * 64) * 128;          // mat0, this wave's half
  const u16* W1 = Wls + 16384 + (h * 64) * 128;  // mat1, this wave's half
  const short8 zero8 = {0, 0, 0, 0, 0, 0, 0, 0};

  for (int t = tstart; t < ntiles; t += gsize) {
    int tile0 = t * 128;
    int ra = tile0 + g * 32 + lrow;
    int rb = ra + 16;
    bool oka = ra < N, okb = rb < N;
    const u16* pa = A + (size_t)(oka ? ra : 0) * 128 + q * 8;
    const u16* pb = A + (size_t)(okb ? rb : 0) * 128 + q * 8;
    short8 av[4], bv[4];
#pragma unroll
    for (int kk = 0; kk < 4; ++kk) {
      av[kk] = *(const short8*)(pa + kk * 32);
      bv[kk] = *(const short8*)(pb + kk * 32);
    }

    f32x4 acc[2][2][4];  // [mat][rowset][j]
#pragma unroll
    for (int o = 0; o < 2; ++o)
#pragma unroll
      for (int i = 0; i < 2; ++i)
#pragma unroll
        for (int j = 0; j < 4; ++j) acc[o][i][j] = (f32x4){0.f, 0.f, 0.f, 0.f};

#pragma unroll
    for (int kk = 0; kk < 4; ++kk) {
      short8 a0 = oka ? av[kk] : zero8;
      short8 a1 = okb ? bv[kk] : zero8;
      int cs = ((kk * 4 + q) ^ lrow) * 8;          // swizzled chunk offset
#pragma unroll
      for (int j = 0; j < 4; ++j) {
        int fr = j * 16 + lrow;                    // (global row &15) == lrow
        short8 b0 = *(const short8*)(W0 + fr * 128 + cs);
        short8 b1 = *(const short8*)(W1 + fr * 128 + cs);
        acc[0][0][j] = __builtin_amdgcn_mfma_f32_16x16x32_bf16(b0, a0, acc[0][0][j], 0, 0, 0);
        acc[0][1][j] = __builtin_amdgcn_mfma_f32_16x16x32_bf16(b0, a1, acc[0][1][j], 0, 0, 0);
        acc[1][0][j] = __builtin_amdgcn_mfma_f32_16x16x32_bf16(b1, a0, acc[1][0][j], 0, 0, 0);
        acc[1][1][j] = __builtin_amdgcn_mfma_f32_16x16x32_bf16(b1, a1, acc[1][1][j], 0, 0, 0);
      }
    }

    // epilogue: lane owns row (tile0 + g*32 + i*16 + lrow);
    // features f = h*64 + j*16 + q*4 + r (4 consecutive per acc quad)
    if (ilv) {
#pragma unroll
      for (int i = 0; i < 2; ++i) {
        int grow = tile0 + g * 32 + i * 16 + lrow;
        if (grow < N) {
#pragma unroll
          for (int o = 0; o < 2; ++o) {
            u16* base = CKV + (size_t)grow * 256 + (o << 3) + ((q & 1) << 2) +
                        ((q >> 1) << 4) + h * 128;
#pragma unroll
            for (int j = 0; j < 4; ++j) {
              f32x4 v = acc[o][i][j];
              ushort4 pk;
              pk.x = f2bf(v[0]); pk.y = f2bf(v[1]); pk.z = f2bf(v[2]); pk.w = f2bf(v[3]);
              *(ushort4*)(base + j * 32) = pk;
            }
          }
        }
      }
    } else {
#pragma unroll
      for (int o = 0; o < 2; ++o) {
        u16* C = o ? CS : CQ;
#pragma unroll
        for (int i = 0; i < 2; ++i) {
          int grow = tile0 + g * 32 + i * 16 + lrow;
          if (grow < N) {
            u16* base = C + (size_t)grow * 128 + q * 4 + h * 64;
#pragma unroll
            for (int j = 0; j < 4; ++j) {
              f32x4 v = acc[o][i][j];
              ushort4 pk;
              pk.x = f2bf(v[0]); pk.y = f2bf(v[1]); pk.z = f2bf(v[2]); pk.w = f2bf(v[3]);
              *(ushort4*)(base + j * 16) = pk;
            }
          }
        }
      }
    }
  }
}

// ---------- CSR build (both layers, rank-based fill) ----------
__global__ __launch_bounds__(256) void csr_count2(
    const int* __restrict__ dst0, const int* __restrict__ dst1,
    int* __restrict__ cnt, int* __restrict__ rank) {
  int t = blockIdx.x * 256 + threadIdx.x;
  if (t < E0N) {
    rank[t] = atomicAdd(&cnt[dst0[t]], 1);
  } else if (t < ET) {
    rank[t] = atomicAdd(&cnt[NE0 + dst1[t - E0N]], 1);
  }
}

__global__ __launch_bounds__(256) void scan1(const int* __restrict__ cnt,
                                             int* __restrict__ excl,
                                             int* __restrict__ blocksums, int N) {
  __shared__ int sh[256];
  int tid = threadIdx.x;
  int base = blockIdx.x * 1024 + tid * 4;
  int v0 = (base + 0 < N) ? cnt[base + 0] : 0;
  int v1 = (base + 1 < N) ? cnt[base + 1] : 0;
  int v2 = (base + 2 < N) ? cnt[base + 2] : 0;
  int v3 = (base + 3 < N) ? cnt[base + 3] : 0;
  int tsum = v0 + v1 + v2 + v3;
  sh[tid] = tsum;
  __syncthreads();
  for (int off = 1; off < 256; off <<= 1) {
    int t2 = (tid >= off) ? sh[tid - off] : 0;
    __syncthreads();
    sh[tid] += t2;
    __syncthreads();
  }
  int incl = sh[tid];
  if (tid == 255) blocksums[blockIdx.x] = incl;
  int run = incl - tsum;
  if (base + 0 < N) excl[base + 0] = run; run += v0;
  if (base + 1 < N) excl[base + 1] = run; run += v1;
  if (base + 2 < N) excl[base + 2] = run; run += v2;
  if (base + 3 < N) excl[base + 3] = run;
}

__global__ void scan2(int* __restrict__ blocksums, int nb) {
  __shared__ int sh[256];
  int tid = threadIdx.x;
  int v = (tid < nb) ? blocksums[tid] : 0;
  sh[tid] = v;
  __syncthreads();
  for (int off = 1; off < 256; off <<= 1) {
    int t2 = (tid >= off) ? sh[tid - off] : 0;
    __syncthreads();
    sh[tid] += t2;
    __syncthreads();
  }
  if (tid < nb) blocksums[tid] = sh[tid] - v;
}

__global__ __launch_bounds__(256) void scan3(int* __restrict__ offs,
                                             const int* __restrict__ blocksums, int N,
                                             int Etot) {
  int t = blockIdx.x * 256 + threadIdx.x;
  if (t < N) offs[t] += blocksums[t >> 10];
  if (t == 0) offs[N] = Etot;
}

__global__ __launch_bounds__(256) void csr_fill2(
    const int* __restrict__ dst0, const int* __restrict__ src0, const int* __restrict__ et0,
    const int* __restrict__ dst1, const int* __restrict__ src1, const int* __restrict__ et1,
    const int* __restrict__ offs, const int* __restrict__ rank,
    int* __restrict__ elist) {
  int t = blockIdx.x * 256 + threadIdx.x;
  if (t < E0N) {
    int p = offs[dst0[t]] + rank[t];
    elist[p] = (src0[t] << 2) | et0[t];
  } else if (t < ET) {
    int t2 = t - E0N;
    int p = offs[NE0 + dst1[t2]] + rank[t];
    elist[p] = (src1[t2] << 2) | et1[t2];
  }
}

// ---------- fused flash attention + skip combine (R9 config, measured best) --
// R10 post-mortem: max-removal + 2048 blocks regressed (92->98); reverted to
// R9 exactly (online max, 1024 persistent blocks, 2-deep pipeline, ve in LDS).
__device__ __forceinline__ float sel4(float s0, float s1, float s2, float s3, int ty) {
  float a = (ty & 1) ? s1 : s0;
  float b = (ty & 1) ? s3 : s2;
  return (ty & 2) ? b : a;
}

#define ATTN_BLOCKS 1024

__global__ __launch_bounds__(256) void attn_fused(
    const int* __restrict__ elist, const int* __restrict__ offs,
    const u16* __restrict__ Q, const u16* __restrict__ KV,
    const float* __restrict__ ke, const float* __restrict__ ve,
    const u16* __restrict__ skipb, float* __restrict__ outp, int N) {
  int lane = threadIdx.x & 63;
  int wid = (blockIdx.x << 2) + (threadIdx.x >> 6);   // global wave id
  int wstride = gridDim.x << 2;
  int which = lane >> 4;   // dst slot within wave
  int sub = lane & 15;     // 16 lanes per dst
  int dim0 = sub * 8;      // 8 consecutive dims per lane; head = sub>>1
  int sub16 = sub * 16;    // u16 offset of this lane's group within a KV row

  // stage ve into LDS once per (persistent) block: [4][136] floats
  __shared__ float vels[4 * 136];
  for (int i = threadIdx.x; i < 512; i += 256) {
    int t = i >> 7, c = i & 127;
    vels[t * 136 + c] = ve[t * 128 + c];
  }
  __syncthreads();

  for (int grp = wid; grp * 4 < N; grp += wstride) {
    int d = grp * 4 + which;
    bool active = d < N;
    int dc = active ? d : 0;

    // Q: 8 dims as 4 packed bf16 pairs (already scaled by 1/sqrt(d))
    uint4 qp = *(const uint4*)(Q + (size_t)dc * D + dim0);
    f32x2 u0 = unpk(qp.x), u1 = unpk(qp.y), u2 = unpk(qp.z), u3 = unpk(qp.w);

    // per-type q . (We ek) : reduce over head (2 lanes)
    float qk0, qk1, qk2, qk3;
#pragma unroll
    for (int ty = 0; ty < 4; ++ty) {
      const float* kt = ke + ty * D + dim0;
      float4 ka = *(const float4*)kt;
      float4 kb = *(const float4*)(kt + 4);
      float p = u0.x * ka.x + u0.y * ka.y + u1.x * ka.z + u1.y * ka.w +
                u2.x * kb.x + u2.y * kb.y + u3.x * kb.z + u3.y * kb.w;
      p += __shfl_xor(p, 1, 64);
      if (ty == 0) qk0 = p; else if (ty == 1) qk1 = p; else if (ty == 2) qk2 = p; else qk3 = p;
    }

    int j0 = active ? offs[d] : 0;
    int j1 = active ? offs[d + 1] : 0;
    int j = j0;

    // --- pipeline prologue: codes for j and j+4 ---
    int cp0, cp1, cp2, cp3;      // current
    int fp0, fp1, fp2, fp3;      // future (j+4)
    {
      int i0 = (j + 0 < j1) ? j + 0 : 0;
      int i1 = (j + 1 < j1) ? j + 1 : 0;
      int i2 = (j + 2 < j1) ? j + 2 : 0;
      int i3 = (j + 3 < j1) ? j + 3 : 0;
      cp0 = elist[i0]; cp1 = elist[i1]; cp2 = elist[i2]; cp3 = elist[i3];
      int k0 = (j + 4 < j1) ? j + 4 : 0;
      int k1 = (j + 5 < j1) ? j + 5 : 0;
      int k2 = (j + 6 < j1) ? j + 6 : 0;
      int k3 = (j + 7 < j1) ? j + 7 : 0;
      fp0 = elist[k0]; fp1 = elist[k1]; fp2 = elist[k2]; fp3 = elist[k3];
    }
    // K+V for current batch (one-time exposed latency per group)
    uint4 ck0 = *(const uint4*)(KV + (size_t)(cp0 >> 2) * 256 + sub16);
    uint4 ck1 = *(const uint4*)(KV + (size_t)(cp1 >> 2) * 256 + sub16);
    uint4 ck2 = *(const uint4*)(KV + (size_t)(cp2 >> 2) * 256 + sub16);
    uint4 ck3 = *(const uint4*)(KV + (size_t)(cp3 >> 2) * 256 + sub16);
    uint4 cw0 = *(const uint4*)(KV + (size_t)(cp0 >> 2) * 256 + sub16 + 8);
    uint4 cw1 = *(const uint4*)(KV + (size_t)(cp1 >> 2) * 256 + sub16 + 8);
    uint4 cw2 = *(const uint4*)(KV + (size_t)(cp2 >> 2) * 256 + sub16 + 8);
    uint4 cw3 = *(const uint4*)(KV + (size_t)(cp3 >> 2) * 256 + sub16 + 8);

    float m = -INFINITY, s = 0.f;
    f32x2 acc01 = {0.f, 0.f}, acc23 = {0.f, 0.f}, acc45 = {0.f, 0.f}, acc67 = {0.f, 0.f};

    while (__any(j < j1)) {
      int jn = j + 4;
      // issue K+V for NEXT batch (codes fp* already resident -> no chain)
      uint4 nk0 = *(const uint4*)(KV + (size_t)(fp0 >> 2) * 256 + sub16);
      uint4 nk1 = *(const uint4*)(KV + (size_t)(fp1 >> 2) * 256 + sub16);
      uint4 nk2 = *(const uint4*)(KV + (size_t)(fp2 >> 2) * 256 + sub16);
      uint4 nk3 = *(const uint4*)(KV + (size_t)(fp3 >> 2) * 256 + sub16);
      uint4 nw0 = *(const uint4*)(KV + (size_t)(fp0 >> 2) * 256 + sub16 + 8);
      uint4 nw1 = *(const uint4*)(KV + (size_t)(fp1 >> 2) * 256 + sub16 + 8);
      uint4 nw2 = *(const uint4*)(KV + (size_t)(fp2 >> 2) * 256 + sub16 + 8);
      uint4 nw3 = *(const uint4*)(KV + (size_t)(fp3 >> 2) * 256 + sub16 + 8);
      // load codes for batch j+8 (consumed next iteration)
      int g0 = (jn + 4 < j1) ? jn + 4 : 0;
      int g1 = (jn + 5 < j1) ? jn + 5 : 0;
      int g2 = (jn + 6 < j1) ? jn + 6 : 0;
      int g3 = (jn + 7 < j1) ? jn + 7 : 0;
      int gp0 = elist[g0], gp1 = elist[g1], gp2 = elist[g2], gp3 = elist[g3];

      int n = j1 - j;
      if (n > 0) {
        int t0 = cp0 & 3, t1 = cp1 & 3, t2 = cp2 & 3, t3 = cp3 & 3;
        // type-value rows from LDS (lgkmcnt -- decoupled from gather FIFO)
        const float* vp0 = vels + t0 * 136 + dim0;
        const float* vp1 = vels + t1 * 136 + dim0;
        const float* vp2 = vels + t2 * 136 + dim0;
        const float* vp3 = vels + t3 * 136 + dim0;
        float4 va0 = *(const float4*)vp0, vb0 = *(const float4*)(vp0 + 4);
        float4 va1 = *(const float4*)vp1, vb1 = *(const float4*)(vp1 + 4);
        float4 va2 = *(const float4*)vp2, vb2 = *(const float4*)(vp2 + 4);
        float4 va3 = *(const float4*)vp3, vb3 = *(const float4*)(vp3 + 4);

        // q . k over lane's 8 dims (bf16 dot2), then head-reduce over 2 lanes
        float p0 = dot2bf(qp.x, ck0.x, dot2bf(qp.y, ck0.y, dot2bf(qp.z, ck0.z, dot2bf(qp.w, ck0.w, 0.f))));
        float p1 = dot2bf(qp.x, ck1.x, dot2bf(qp.y, ck1.y, dot2bf(qp.z, ck1.z, dot2bf(qp.w, ck1.w, 0.f))));
        float p2 = dot2bf(qp.x, ck2.x, dot2bf(qp.y, ck2.y, dot2bf(qp.z, ck2.z, dot2bf(qp.w, ck2.w, 0.f))));
        float p3 = dot2bf(qp.x, ck3.x, dot2bf(qp.y, ck3.y, dot2bf(qp.z, ck3.z, dot2bf(qp.w, ck3.w, 0.f))));
        p0 += __shfl_xor(p0, 1, 64);
        p1 += __shfl_xor(p1, 1, 64);
        p2 += __shfl_xor(p2, 1, 64);
        p3 += __shfl_xor(p3, 1, 64);

        float l0 = p0 + sel4(qk0, qk1, qk2, qk3, t0);
        float l1 = p1 + sel4(qk0, qk1, qk2, qk3, t1);
        float l2 = p2 + sel4(qk0, qk1, qk2, qk3, t2);
        float l3 = p3 + sel4(qk0, qk1, qk2, qk3, t3);
        l0 = l0 >= 0.f ? l0 : 0.2f * l0;
        l1 = l1 >= 0.f ? l1 : 0.2f * l1;
        l2 = l2 >= 0.f ? l2 : 0.2f * l2;
        l3 = l3 >= 0.f ? l3 : 0.2f * l3;
        if (n < 2) l1 = -INFINITY;
        if (n < 3) l2 = -INFINITY;
        if (n < 4) l3 = -INFINITY;
        float mb = fmaxf(fmaxf(l0, l1), fmaxf(l2, l3));
        float mn = fmaxf(m, mb);
        float f = __expf(m - mn);
        float a0 = __expf(l0 - mn);
        float a1 = __expf(l1 - mn);
        float a2 = __expf(l2 - mn);
        float a3 = __expf(l3 - mn);
        s = s * f + ((a0 + a1) + (a2 + a3));
        f32x2 ff = {f, f};
        acc01 *= ff; acc23 *= ff; acc45 *= ff; acc67 *= ff;
        f32x2 aa0 = {a0, a0}, aa1 = {a1, a1}, aa2 = {a2, a2}, aa3 = {a3, a3};
        acc01 = fma2(aa0, unpk(cw0.x) + (f32x2){va0.x, va0.y}, acc01);
        acc23 = fma2(aa0, unpk(cw0.y) + (f32x2){va0.z, va0.w}, acc23);
        acc45 = fma2(aa0, unpk(cw0.z) + (f32x2){vb0.x, vb0.y}, acc45);
        acc67 = fma2(aa0, unpk(cw0.w) + (f32x2){vb0.z, vb0.w}, acc67);
        acc01 = fma2(aa1, unpk(cw1.x) + (f32x2){va1.x, va1.y}, acc01);
        acc23 = fma2(aa1, unpk(cw1.y) + (f32x2){va1.z, va1.w}, acc23);
        acc45 = fma2(aa1, unpk(cw1.z) + (f32x2){vb1.x, vb1.y}, acc45);
        acc67 = fma2(aa1, unpk(cw1.w) + (f32x2){vb1.z, vb1.w}, acc67);
        acc01 = fma2(aa2, unpk(cw2.x) + (f32x2){va2.x, va2.y}, acc01);
        acc23 = fma2(aa2, unpk(cw2.y) + (f32x2){va2.z, va2.w}, acc23);
        acc45 = fma2(aa2, unpk(cw2.z) + (f32x2){vb2.x, vb2.y}, acc45);
        acc67 = fma2(aa2, unpk(cw2.w) + (f32x2){vb2.z, vb2.w}, acc67);
        acc01 = fma2(aa3, unpk(cw3.x) + (f32x2){va3.x, va3.y}, acc01);
        acc23 = fma2(aa3, unpk(cw3.y) + (f32x2){va3.z, va3.w}, acc23);
        acc45 = fma2(aa3, unpk(cw3.z) + (f32x2){vb3.x, vb3.y}, acc45);
        acc67 = fma2(aa3, unpk(cw3.w) + (f32x2){vb3.z, vb3.w}, acc67);
        m = mn;
      }
      // rotate pipeline
      cp0 = fp0; cp1 = fp1; cp2 = fp2; cp3 = fp3;
      fp0 = gp0; fp1 = gp1; fp2 = gp2; fp3 = gp3;
      ck0 = nk0; ck1 = nk1; ck2 = nk2; ck3 = nk3;
      cw0 = nw0; cw1 = nw1; cw2 = nw2; cw3 = nw3;
      j = jn;
    }
    if (active) {
      float inv = 1.f / (s + 1e-16f);
      float hf = 0.5f * inv;
      uint4 sk = *(const uint4*)(skipb + (size_t)d * D + dim0);
      f32x2 s0 = unpk(sk.x), s1 = unpk(sk.y), s2 = unpk(sk.z), s3 = unpk(sk.w);
      float* op = outp + (size_t)d * D + dim0;
      float4 o0, o1;
      o0.x = 0.5f * s0.x + hf * acc01.x;
      o0.y = 0.5f * s0.y + hf * acc01.y;
      o0.z = 0.5f * s1.x + hf * acc23.x;
      o0.w = 0.5f * s1.y + hf * acc23.y;
      o1.x = 0.5f * s2.x + hf * acc45.x;
      o1.y = 0.5f * s2.y + hf * acc45.y;
      o1.z = 0.5f * s3.x + hf * acc67.x;
      o1.w = 0.5f * s3.y + hf * acc67.y;
      *(float4*)op = o0;
      *(float4*)(op + 4) = o1;
    }
  }
}

// ---------- batch norm ----------
__global__ __launch_bounds__(256) void bn_reduce(const float* __restrict__ h,
                                                 float* __restrict__ sums, int N) {
  int c = threadIdx.x & 127;
  int rofs = threadIdx.x >> 7;
  float s0 = 0.f, s1 = 0.f;
  for (int r = blockIdx.x * 2 + rofs; r < N; r += gridDim.x * 2) {
    float v = h[(size_t)r * 128 + c];
    s0 += v;
    s1 += v * v;
  }
  __shared__ float ls[256], lq[256];
  ls[threadIdx.x] = s0;
  lq[threadIdx.x] = s1;
  __syncthreads();
  if (threadIdx.x < 128) {
    atomicAdd(&sums[c], ls[threadIdx.x] + ls[threadIdx.x + 128]);
    atomicAdd(&sums[128 + c], lq[threadIdx.x] + lq[threadIdx.x + 128]);
  }
}

__global__ __launch_bounds__(256) void bn_apply(const float* __restrict__ h,
                                                u16* __restrict__ hbf,
                                                const float* __restrict__ sums,
                                                const float* __restrict__ gamma,
                                                const float* __restrict__ beta,
                                                float invN, int total) {
  __shared__ float sc[128], sh[128];
  int tid = threadIdx.x;
  if (tid < 128) {
    float mu = sums[tid] * invN;
    float var = sums[128 + tid] * invN - mu * mu;
    float inv = rsqrtf(var + 1e-5f);
    float s = gamma[tid] * inv;
    sc[tid] = s;
    sh[tid] = beta[tid] - mu * s;
  }
  __syncthreads();
  int i = blockIdx.x * 256 + tid;
  if (i < total) {
    int c = i & 127;
    hbf[i] = f2bf(h[i] * sc[c] + sh[c]);
  }
}

// ---------- launch ----------
extern "C" void kernel_launch(void* const* d_in, const int* in_sizes, int n_in,
                              void* d_out, int out_size, void* d_ws, size_t ws_size,
                              hipStream_t stream) {
  const float* x        = (const float*)d_in[0];
  const int*   ei0      = (const int*)d_in[1];
  const int*   et0      = (const int*)d_in[2];
  const int*   ei1      = (const int*)d_in[3];
  const int*   et1      = (const int*)d_in[4];
  const float* emb_type = (const float*)d_in[5];
  const float* emb_attr = (const float*)d_in[6];
  const float* v2e_Wq   = (const float*)d_in[7];
  const float* v2e_Wk   = (const float*)d_in[8];
  const float* v2e_Wv   = (const float*)d_in[9];
  const float* v2e_We   = (const float*)d_in[10];
  const float* v2e_Wsk  = (const float*)d_in[11];
  const float* e2_Wq    = (const float*)d_in[12];
  const float* e2_Wk    = (const float*)d_in[13];
  const float* e2_Wv    = (const float*)d_in[14];
  const float* e2_We    = (const float*)d_in[15];
  const float* e2_Wsk   = (const float*)d_in[16];
  const float* bn_gamma = (const float*)d_in[17];
  const float* bn_beta  = (const float*)d_in[18];
  float* out = (float*)d_out;

  // workspace layout
  char* wsb = (char*)d_ws;
  size_t off = 0;
  u16* xb  = (u16*)(wsb + off);  off += (size_t)NSRC * D * 2;
  u16* KVb = (u16*)(wsb + off);  off += (size_t)NSRC * D * 2 * 2;  // interleaved K|V
  u16* Qb  = (u16*)(wsb + off);  off += (size_t)NE0 * D * 2;
  u16* Sb  = (u16*)(wsb + off);  off += (size_t)NE0 * D * 2;
  float* hb = (float*)(wsb + off); off += (size_t)NE0 * D * 4;
  u16* hbf = (u16*)(wsb + off);  off += (size_t)NE0 * D * 2;
  u16* wtAll = (u16*)(wsb + off); off += 8 * 16384 * 2;
  int* elist = (int*)(wsb + off);  off += (size_t)ET * 4;
  int* rank  = (int*)(wsb + off);  off += (size_t)ET * 4;
  int* offs  = (int*)(wsb + off);  off += ((size_t)NT + 8) * 4;
  int* bsums = (int*)(wsb + off);  off += 1024;
  float* kv  = (float*)(wsb + off); off += 4 * 512 * 4;
  float* bnsums = (float*)(wsb + off); off += 256 * 4;  // sum[128] | sumsq[128]

  u16* wtK0 = wtAll + 0 * 16384;
  u16* wtV0 = wtAll + 1 * 16384;
  u16* wtQ0 = wtAll + 2 * 16384;
  u16* wtS0 = wtAll + 3 * 16384;
  u16* wtK1 = wtAll + 4 * 16384;
  u16* wtV1 = wtAll + 5 * 16384;
  u16* wtQ1 = wtAll + 6 * 16384;
  u16* wtS1 = wtAll + 7 * 16384;
  float* kep0 = kv;
  float* vep0 = kv + 512;
  float* kep1 = kv + 1024;
  float* vep1 = kv + 1536;

  const int* src0 = ei0;
  const int* dst0 = ei0 + E0N;
  const int* src1 = ei1;
  const int* dst1 = ei1 + E1N;

  // 1: mega-prep (cast + weights + embs + zeroing)
  prep_all<<<BC + 64 + 4 + BZ + 1, 256, 0, stream>>>(
      x, xb, v2e_Wk, v2e_Wv, v2e_Wq, v2e_Wsk, e2_Wk, e2_Wv, e2_Wq, e2_Wsk,
      wtAll, emb_type, emb_attr, v2e_We, e2_We, kv, offs, bnsums);

  // 2-6: CSR for both layers
  csr_count2<<<(ET + 255) / 256, 256, 0, stream>>>(dst0, dst1, offs, rank);
  {
    int nb = (NT + 1023) / 1024;
    scan1<<<nb, 256, 0, stream>>>(offs, offs, bsums, NT);
    scan2<<<1, 256, 0, stream>>>(bsums, nb);
    scan3<<<(NT + 255) / 256, 256, 0, stream>>>(offs, bsums, NT, ET);
  }
  csr_fill2<<<(ET + 255) / 256, 256, 0, stream>>>(dst0, src0, et0, dst1, src1, et1,
                                                  offs, rank, elist);

  // 7-10: layer 0
  {
    int nKV = (NSRC + 127) / 128, nQS = (NE0 + 127) / 128;
    int grid = 512;
    int gKV = (int)((long)grid * nKV / (nKV + nQS));
    if (gKV < 1) gKV = 1;
    if (gKV >= grid) gKV = grid - 1;
    gemm_quad<<<grid, 512, 0, stream>>>(xb, wtK0, wtV0, KVb, NSRC, nKV,
                                        wtQ0, wtS0, Qb, Sb, NE0, gKV);
  }
  attn_fused<<<ATTN_BLOCKS, 256, 0, stream>>>(elist, offs, Qb, KVb, kep0, vep0,
                                              Sb, hb, NE0);
  bn_reduce<<<256, 256, 0, stream>>>(hb, bnsums, NE0);
  bn_apply<<<(NE0 * D + 255) / 256, 256, 0, stream>>>(hb, hbf, bnsums, bn_gamma, bn_beta,
                                                      1.0f / (float)NE0, NE0 * D);

  // 11-12: layer 1
  {
    int nKV = (NE0 + 127) / 128, nQS = (NE1 + 127) / 128;
    int grid = 512;
    int gKV = (int)((long)grid * nKV / (nKV + nQS));
    if (gKV < 1) gKV = 1;
    if (gKV >= grid) gKV = grid - 1;
    gemm_quad<<<grid, 512, 0, stream>>>(hbf, wtK1, wtV1, KVb, NE0, nKV,
                                        wtQ1, wtS1, Qb, Sb, NE1, gKV);
  }
  attn_fused<<<ATTN_BLOCKS, 256, 0, stream>>>(elist, offs + NE0, Qb, KVb, kep1, vep1,
                                              Sb, out, NE1);
}

// Round 12
// 584.061 us; speedup vs baseline: 1.4495x; 1.4495x over previous
//
#include <hip/hip_runtime.h>
#include <cstdint>
#include <cstddef>

#define D 128
#define H 8
#define NSRC 200000
#define NE0  100000
#define NE1  50000
#define E0N  1000000
#define E1N  500000
#define NT   (NE0 + NE1)
#define ET   (E0N + E1N)

typedef unsigned short u16;
typedef __attribute__((ext_vector_type(8))) short short8;
typedef __attribute__((ext_vector_type(4))) float f32x4;
typedef __attribute__((ext_vector_type(2))) float f32x2;

// ---------- bf16 helpers ----------
__device__ __forceinline__ u16 f2bf(float f) {
  unsigned u = __float_as_uint(f);
  unsigned r = (u + 0x7fffu + ((u >> 16) & 1u)) >> 16;  // RNE
  return (u16)r;
}
__device__ __forceinline__ float bf2f(u16 u) {
  return __uint_as_float(((unsigned)u) << 16);
}
// unpack 2 packed bf16 (low = even dim) -> f32x2
__device__ __forceinline__ f32x2 unpk(unsigned u) {
  f32x2 r;
  r.x = __uint_as_float(u << 16);
  r.y = __uint_as_float(u & 0xffff0000u);
  return r;
}
// bf16 pair dot with f32 accumulate: d = a.lo*b.lo + a.hi*b.hi + c
__device__ __forceinline__ float dot2bf(unsigned a, unsigned b, float c) {
  float d;
  asm("v_dot2_f32_bf16 %0, %1, %2, %3" : "=v"(d) : "v"(a), "v"(b), "v"(c));
  return d;
}
__device__ __forceinline__ f32x2 fma2(f32x2 a, f32x2 b, f32x2 c) {
  return __builtin_elementwise_fma(a, b, c);
}

// ---------- mega-prep: x cast + weight transpose + emb GEMMs + zero-fill ----------
// block roles: [0,BC) cast | [BC,BC+64) weights | +4 embs | +BZ zero offs | +1 zero bn
#define BC 25000            // (NSRC*D/4)/256
#define BZ 147              // ceil((NT+1)/1024)
static_assert((size_t)BZ * 1024 >= NT + 1, "offs zero-fill must cover NT+1 entries");
__global__ __launch_bounds__(256) void prep_all(
    const float* __restrict__ x, u16* __restrict__ xb,
    const float* w0, const float* w1, const float* w2, const float* w3,
    const float* w4, const float* w5, const float* w6, const float* w7,
    u16* __restrict__ wt,
    const float* __restrict__ embA, const float* __restrict__ embB,
    const float* __restrict__ We0, const float* __restrict__ We1,
    float* __restrict__ kv,
    int* __restrict__ offs, float* __restrict__ bnsums) {
  int b = blockIdx.x;
  if (b < BC) {
    int i = b * 256 + threadIdx.x;
    float4 a = ((const float4*)x)[i];
    ushort4 o;
    o.x = f2bf(a.x); o.y = f2bf(a.y); o.z = f2bf(a.z); o.w = f2bf(a.w);
    ((ushort4*)xb)[i] = o;
  } else if (b < BC + 64) {
    int bb = b - BC;
    const float* wsrc[8] = {w0, w1, w2, w3, w4, w5, w6, w7};
    int mat = bb >> 3;
    int blk = bb & 7;
    const float* W = wsrc[mat];
    // fold 1/sqrt(d)=0.25 into Wq (mats 2 and 6) so Q comes out pre-scaled
    float sc = ((mat & 3) == 2) ? 0.25f : 1.0f;
    u16* out = wt + mat * 16384;
    for (int i = blk * 2048 + threadIdx.x; i < (blk + 1) * 2048; i += 256) {
      int n = i >> 7, k = i & 127;
      out[i] = f2bf(W[k * 128 + n] * sc);
    }
  } else if (b < BC + 68) {
    int bb = b - BC - 64;
    int mat = bb >> 1;
    int t = (bb & 1) * 256 + threadIdx.x;
    const float* We = mat ? We1 : We0;
    float* keOut = kv + mat * 1024;
    float* veOut = keOut + 512;
    int r = t >> 7, c = t & 127;
    float s0 = 0.f, s1 = 0.f;
    for (int k = 0; k < 128; ++k) {
      float w = We[k * 128 + c];
      s0 += embA[r * 128 + k] * w;
      s1 += embB[r * 128 + k] * w;
    }
    keOut[t] = s0;
    veOut[t] = s1;
  } else if (b < BC + 68 + BZ) {
    int base = (b - BC - 68) * 1024 + threadIdx.x * 4;
#pragma unroll
    for (int i = 0; i < 4; ++i)
      if (base + i < NT + 1) offs[base + i] = 0;
  } else {
    bnsums[threadIdx.x] = 0.f;  // 256 floats = bnsum|bnsq
  }
}

// ---------- quad-output MFMA GEMM, weights-in-LDS (R5 design, reverted) ------
// R11 post-mortem: persistent 512-block gemm REGRESSED hard (197-222us,
// FETCH 39->346MB, WRITE 150->294MB): the dense 2344-block grid's L2/L3
// locality (neighbor tiles resident simultaneously) was load-bearing;
// tile-striding from few long-lived blocks destroyed it. Reverted exactly.
__global__ __launch_bounds__(512, 4) void gemm_quad(
    const u16* __restrict__ A,
    const u16* __restrict__ WtK, const u16* __restrict__ WtV,
    u16* __restrict__ CKV, int NA, int nKV,
    const u16* __restrict__ WtQ, const u16* __restrict__ WtS,
    u16* __restrict__ CQ, u16* __restrict__ CS, int NB) {
  int bb = blockIdx.x;
  const u16 *Wt0, *Wt1;
  int N, tile0;
  bool ilv = (bb < nKV);
  if (ilv) {
    Wt0 = WtK; Wt1 = WtV; N = NA; tile0 = bb * 128;
  } else {
    Wt0 = WtQ; Wt1 = WtS; N = NB; tile0 = (bb - nKV) * 128;
  }
  int tid = threadIdx.x;
  int w = tid >> 6, lane = tid & 63;
  int g = w >> 1;          // row group: rows [g*32, g*32+32)
  int h = w & 1;           // feature half: features [h*64, h*64+64)
  int lrow = lane & 15, q = lane >> 4;

  __shared__ u16 Wls[2 * 128 * 128];  // 64 KB: both mats, chunk-XOR swizzled

  // 1) issue weight-staging loads FIRST (same 64 KB for all blocks -> L2-hot)
  uint4 wv[8];
#pragma unroll
  for (int i = 0; i < 8; ++i) {
    int m = i * 512 + tid;                       // 4096 x 16B chunks
    const u16* Wsrc = (m >> 11) ? Wt1 : Wt0;
    wv[i] = *(const uint4*)(Wsrc + (size_t)(m & 2047) * 8);
  }

  // 2) issue A-fragment loads (whole K-extent to regs); newer in VMEM FIFO,
  //    so staging's waitcnt leaves them in flight.
  int ra = tile0 + g * 32 + lrow;
  int rb = ra + 16;
  bool oka = ra < N, okb = rb < N;
  const u16* pa = A + (size_t)(oka ? ra : 0) * 128 + q * 8;
  const u16* pb = A + (size_t)(okb ? rb : 0) * 128 + q * 8;
  short8 av[4], bv[4];
#pragma unroll
  for (int kk = 0; kk < 4; ++kk) {
    av[kk] = *(const short8*)(pa + kk * 32);
    bv[kk] = *(const short8*)(pb + kk * 32);
  }

  // 3) LDS write (chunk-XOR swizzle: LDS(row,c) = W(row, c ^ (row&15)))
#pragma unroll
  for (int i = 0; i < 8; ++i) {
    int m = i * 512 + tid;
    int row = (m & 2047) >> 4, c = m & 15;
    *(uint4*)(Wls + (m >> 11) * 16384 + row * 128 + (c ^ (row & 15)) * 8) = wv[i];
  }
  __syncthreads();

  const u16* W0 = Wls + (h * 64) * 128;          // mat0, this wave's half
  const u16* W1 = Wls + 16384 + (h * 64) * 128;  // mat1, this wave's half

  f32x4 acc[2][2][4];  // [mat][rowset][j]
#pragma unroll
  for (int o = 0; o < 2; ++o)
#pragma unroll
    for (int i = 0; i < 2; ++i)
#pragma unroll
      for (int j = 0; j < 4; ++j) acc[o][i][j] = (f32x4){0.f, 0.f, 0.f, 0.f};

  const short8 zero8 = {0, 0, 0, 0, 0, 0, 0, 0};
#pragma unroll
  for (int kk = 0; kk < 4; ++kk) {
    short8 a0 = oka ? av[kk] : zero8;
    short8 a1 = okb ? bv[kk] : zero8;
    int cs = ((kk * 4 + q) ^ lrow) * 8;          // swizzled chunk offset
#pragma unroll
    for (int j = 0; j < 4; ++j) {
      int fr = j * 16 + lrow;                    // (global row &15) == lrow
      short8 b0 = *(const short8*)(W0 + fr * 128 + cs);
      short8 b1 = *(const short8*)(W1 + fr * 128 + cs);
      acc[0][0][j] = __builtin_amdgcn_mfma_f32_16x16x32_bf16(b0, a0, acc[0][0][j], 0, 0, 0);
      acc[0][1][j] = __builtin_amdgcn_mfma_f32_16x16x32_bf16(b0, a1, acc[0][1][j], 0, 0, 0);
      acc[1][0][j] = __builtin_amdgcn_mfma_f32_16x16x32_bf16(b1, a0, acc[1][0][j], 0, 0, 0);
      acc[1][1][j] = __builtin_amdgcn_mfma_f32_16x16x32_bf16(b1, a1, acc[1][1][j], 0, 0, 0);
    }
  }

  // epilogue: lane owns row (tile0 + g*32 + i*16 + lrow);
  // features f = h*64 + j*16 + q*4 + r (4 consecutive per acc quad)
  if (ilv) {
#pragma unroll
    for (int i = 0; i < 2; ++i) {
      int grow = tile0 + g * 32 + i * 16 + lrow;
      if (grow < N) {
#pragma unroll
        for (int o = 0; o < 2; ++o) {
          u16* base = CKV + (size_t)grow * 256 + (o << 3) + ((q & 1) << 2) +
                      ((q >> 1) << 4) + h * 128;
#pragma unroll
          for (int j = 0; j < 4; ++j) {
            f32x4 v = acc[o][i][j];
            ushort4 pk;
            pk.x = f2bf(v[0]); pk.y = f2bf(v[1]); pk.z = f2bf(v[2]); pk.w = f2bf(v[3]);
            *(ushort4*)(base + j * 32) = pk;
          }
        }
      }
    }
  } else {
#pragma unroll
    for (int o = 0; o < 2; ++o) {
      u16* C = o ? CS : CQ;
#pragma unroll
      for (int i = 0; i < 2; ++i) {
        int grow = tile0 + g * 32 + i * 16 + lrow;
        if (grow < N) {
          u16* base = C + (size_t)grow * 128 + q * 4 + h * 64;
#pragma unroll
          for (int j = 0; j < 4; ++j) {
            f32x4 v = acc[o][i][j];
            ushort4 pk;
            pk.x = f2bf(v[0]); pk.y = f2bf(v[1]); pk.z = f2bf(v[2]); pk.w = f2bf(v[3]);
            *(ushort4*)(base + j * 16) = pk;
          }
        }
      }
    }
  }
}

// ---------- CSR build (both layers, rank-based fill) ----------
__global__ __launch_bounds__(256) void csr_count2(
    const int* __restrict__ dst0, const int* __restrict__ dst1,
    int* __restrict__ cnt, int* __restrict__ rank) {
  int t = blockIdx.x * 256 + threadIdx.x;
  if (t < E0N) {
    rank[t] = atomicAdd(&cnt[dst0[t]], 1);
  } else if (t < ET) {
    rank[t] = atomicAdd(&cnt[NE0 + dst1[t - E0N]], 1);
  }
}

__global__ __launch_bounds__(256) void scan1(const int* __restrict__ cnt,
                                             int* __restrict__ excl,
                                             int* __restrict__ blocksums, int N) {
  __shared__ int sh[256];
  int tid = threadIdx.x;
  int base = blockIdx.x * 1024 + tid * 4;
  int v0 = (base + 0 < N) ? cnt[base + 0] : 0;
  int v1 = (base + 1 < N) ? cnt[base + 1] : 0;
  int v2 = (base + 2 < N) ? cnt[base + 2] : 0;
  int v3 = (base + 3 < N) ? cnt[base + 3] : 0;
  int tsum = v0 + v1 + v2 + v3;
  sh[tid] = tsum;
  __syncthreads();
  for (int off = 1; off < 256; off <<= 1) {
    int t2 = (tid >= off) ? sh[tid - off] : 0;
    __syncthreads();
    sh[tid] += t2;
    __syncthreads();
  }
  int incl = sh[tid];
  if (tid == 255) blocksums[blockIdx.x] = incl;
  int run = incl - tsum;
  if (base + 0 < N) excl[base + 0] = run; run += v0;
  if (base + 1 < N) excl[base + 1] = run; run += v1;
  if (base + 2 < N) excl[base + 2] = run; run += v2;
  if (base + 3 < N) excl[base + 3] = run;
}

__global__ void scan2(int* __restrict__ blocksums, int nb) {
  __shared__ int sh[256];
  int tid = threadIdx.x;
  int v = (tid < nb) ? blocksums[tid] : 0;
  sh[tid] = v;
  __syncthreads();
  for (int off = 1; off < 256; off <<= 1) {
    int t2 = (tid >= off) ? sh[tid - off] : 0;
    __syncthreads();
    sh[tid] += t2;
    __syncthreads();
  }
  if (tid < nb) blocksums[tid] = sh[tid] - v;
}

__global__ __launch_bounds__(256) void scan3(int* __restrict__ offs,
                                             const int* __restrict__ blocksums, int N,
                                             int Etot) {
  int t = blockIdx.x * 256 + threadIdx.x;
  if (t < N) offs[t] += blocksums[t >> 10];
  if (t == 0) offs[N] = Etot;
}

__global__ __launch_bounds__(256) void csr_fill2(
    const int* __restrict__ dst0, const int* __restrict__ src0, const int* __restrict__ et0,
    const int* __restrict__ dst1, const int* __restrict__ src1, const int* __restrict__ et1,
    const int* __restrict__ offs, const int* __restrict__ rank,
    int* __restrict__ elist) {
  int t = blockIdx.x * 256 + threadIdx.x;
  if (t < E0N) {
    int p = offs[dst0[t]] + rank[t];
    elist[p] = (src0[t] << 2) | et0[t];
  } else if (t < ET) {
    int t2 = t - E0N;
    int p = offs[NE0 + dst1[t2]] + rank[t];
    elist[p] = (src1[t2] << 2) | et1[t2];
  }
}

// ---------- fused flash attention + skip combine + optional BN-stats (R12) ---
// Attn body = R9 (measured best: 92us L0). NEW: when bnsums!=nullptr (layer 0)
// each lane accumulates sum/sumsq of its 8 output dims across all its groups
// in registers, reduces via LDS atomics at block end, then 256 global atomics
// per block -> bn_reduce kernel (51MB re-read of hb + launch) eliminated.
__device__ __forceinline__ float sel4(float s0, float s1, float s2, float s3, int ty) {
  float a = (ty & 1) ? s1 : s0;
  float b = (ty & 1) ? s3 : s2;
  return (ty & 2) ? b : a;
}

#define ATTN_BLOCKS 1024

__global__ __launch_bounds__(256) void attn_fused(
    const int* __restrict__ elist, const int* __restrict__ offs,
    const u16* __restrict__ Q, const u16* __restrict__ KV,
    const float* __restrict__ ke, const float* __restrict__ ve,
    const u16* __restrict__ skipb, float* __restrict__ outp, int N,
    float* __restrict__ bnsums) {
  int lane = threadIdx.x & 63;
  int wid = (blockIdx.x << 2) + (threadIdx.x >> 6);   // global wave id
  int wstride = gridDim.x << 2;
  int which = lane >> 4;   // dst slot within wave
  int sub = lane & 15;     // 16 lanes per dst
  int dim0 = sub * 8;      // 8 consecutive dims per lane; head = sub>>1
  int sub16 = sub * 16;    // u16 offset of this lane's group within a KV row
  bool dosum = (bnsums != nullptr);

  // stage ve into LDS once per (persistent) block: [4][136] floats
  __shared__ float vels[4 * 136];
  __shared__ float bsum[128], bsq[128];
  for (int i = threadIdx.x; i < 512; i += 256) {
    int t = i >> 7, c = i & 127;
    vels[t * 136 + c] = ve[t * 128 + c];
  }
  if (threadIdx.x < 128) {
    bsum[threadIdx.x] = 0.f;
    bsq[threadIdx.x] = 0.f;
  }
  __syncthreads();

  float ls[8], lq[8];
#pragma unroll
  for (int i = 0; i < 8; ++i) { ls[i] = 0.f; lq[i] = 0.f; }

  for (int grp = wid; grp * 4 < N; grp += wstride) {
    int d = grp * 4 + which;
    bool active = d < N;
    int dc = active ? d : 0;

    // Q: 8 dims as 4 packed bf16 pairs (already scaled by 1/sqrt(d))
    uint4 qp = *(const uint4*)(Q + (size_t)dc * D + dim0);
    f32x2 u0 = unpk(qp.x), u1 = unpk(qp.y), u2 = unpk(qp.z), u3 = unpk(qp.w);

    // per-type q . (We ek) : reduce over head (2 lanes)
    float qk0, qk1, qk2, qk3;
#pragma unroll
    for (int ty = 0; ty < 4; ++ty) {
      const float* kt = ke + ty * D + dim0;
      float4 ka = *(const float4*)kt;
      float4 kb = *(const float4*)(kt + 4);
      float p = u0.x * ka.x + u0.y * ka.y + u1.x * ka.z + u1.y * ka.w +
                u2.x * kb.x + u2.y * kb.y + u3.x * kb.z + u3.y * kb.w;
      p += __shfl_xor(p, 1, 64);
      if (ty == 0) qk0 = p; else if (ty == 1) qk1 = p; else if (ty == 2) qk2 = p; else qk3 = p;
    }

    int j0 = active ? offs[d] : 0;
    int j1 = active ? offs[d + 1] : 0;
    int j = j0;

    // --- pipeline prologue: codes for j and j+4 ---
    int cp0, cp1, cp2, cp3;      // current
    int fp0, fp1, fp2, fp3;      // future (j+4)
    {
      int i0 = (j + 0 < j1) ? j + 0 : 0;
      int i1 = (j + 1 < j1) ? j + 1 : 0;
      int i2 = (j + 2 < j1) ? j + 2 : 0;
      int i3 = (j + 3 < j1) ? j + 3 : 0;
      cp0 = elist[i0]; cp1 = elist[i1]; cp2 = elist[i2]; cp3 = elist[i3];
      int k0 = (j + 4 < j1) ? j + 4 : 0;
      int k1 = (j + 5 < j1) ? j + 5 : 0;
      int k2 = (j + 6 < j1) ? j + 6 : 0;
      int k3 = (j + 7 < j1) ? j + 7 : 0;
      fp0 = elist[k0]; fp1 = elist[k1]; fp2 = elist[k2]; fp3 = elist[k3];
    }
    // K+V for current batch (one-time exposed latency per group)
    uint4 ck0 = *(const uint4*)(KV + (size_t)(cp0 >> 2) * 256 + sub16);
    uint4 ck1 = *(const uint4*)(KV + (size_t)(cp1 >> 2) * 256 + sub16);
    uint4 ck2 = *(const uint4*)(KV + (size_t)(cp2 >> 2) * 256 + sub16);
    uint4 ck3 = *(const uint4*)(KV + (size_t)(cp3 >> 2) * 256 + sub16);
    uint4 cw0 = *(const uint4*)(KV + (size_t)(cp0 >> 2) * 256 + sub16 + 8);
    uint4 cw1 = *(const uint4*)(KV + (size_t)(cp1 >> 2) * 256 + sub16 + 8);
    uint4 cw2 = *(const uint4*)(KV + (size_t)(cp2 >> 2) * 256 + sub16 + 8);
    uint4 cw3 = *(const uint4*)(KV + (size_t)(cp3 >> 2) * 256 + sub16 + 8);

    float m = -INFINITY, s = 0.f;
    f32x2 acc01 = {0.f, 0.f}, acc23 = {0.f, 0.f}, acc45 = {0.f, 0.f}, acc67 = {0.f, 0.f};

    while (__any(j < j1)) {
      int jn = j + 4;
      // issue K+V for NEXT batch (codes fp* already resident -> no chain)
      uint4 nk0 = *(const uint4*)(KV + (size_t)(fp0 >> 2) * 256 + sub16);
      uint4 nk1 = *(const uint4*)(KV + (size_t)(fp1 >> 2) * 256 + sub16);
      uint4 nk2 = *(const uint4*)(KV + (size_t)(fp2 >> 2) * 256 + sub16);
      uint4 nk3 = *(const uint4*)(KV + (size_t)(fp3 >> 2) * 256 + sub16);
      uint4 nw0 = *(const uint4*)(KV + (size_t)(fp0 >> 2) * 256 + sub16 + 8);
      uint4 nw1 = *(const uint4*)(KV + (size_t)(fp1 >> 2) * 256 + sub16 + 8);
      uint4 nw2 = *(const uint4*)(KV + (size_t)(fp2 >> 2) * 256 + sub16 + 8);
      uint4 nw3 = *(const uint4*)(KV + (size_t)(fp3 >> 2) * 256 + sub16 + 8);
      // load codes for batch j+8 (consumed next iteration)
      int g0 = (jn + 4 < j1) ? jn + 4 : 0;
      int g1 = (jn + 5 < j1) ? jn + 5 : 0;
      int g2 = (jn + 6 < j1) ? jn + 6 : 0;
      int g3 = (jn + 7 < j1) ? jn + 7 : 0;
      int gp0 = elist[g0], gp1 = elist[g1], gp2 = elist[g2], gp3 = elist[g3];

      int n = j1 - j;
      if (n > 0) {
        int t0 = cp0 & 3, t1 = cp1 & 3, t2 = cp2 & 3, t3 = cp3 & 3;
        // type-value rows from LDS (lgkmcnt -- decoupled from gather FIFO)
        const float* vp0 = vels + t0 * 136 + dim0;
        const float* vp1 = vels + t1 * 136 + dim0;
        const float* vp2 = vels + t2 * 136 + dim0;
        const float* vp3 = vels + t3 * 136 + dim0;
        float4 va0 = *(const float4*)vp0, vb0 = *(const float4*)(vp0 + 4);
        float4 va1 = *(const float4*)vp1, vb1 = *(const float4*)(vp1 + 4);
        float4 va2 = *(const float4*)vp2, vb2 = *(const float4*)(vp2 + 4);
        float4 va3 = *(const float4*)vp3, vb3 = *(const float4*)(vp3 + 4);

        // q . k over lane's 8 dims (bf16 dot2), then head-reduce over 2 lanes
        float p0 = dot2bf(qp.x, ck0.x, dot2bf(qp.y, ck0.y, dot2bf(qp.z, ck0.z, dot2bf(qp.w, ck0.w, 0.f))));
        float p1 = dot2bf(qp.x, ck1.x, dot2bf(qp.y, ck1.y, dot2bf(qp.z, ck1.z, dot2bf(qp.w, ck1.w, 0.f))));
        float p2 = dot2bf(qp.x, ck2.x, dot2bf(qp.y, ck2.y, dot2bf(qp.z, ck2.z, dot2bf(qp.w, ck2.w, 0.f))));
        float p3 = dot2bf(qp.x, ck3.x, dot2bf(qp.y, ck3.y, dot2bf(qp.z, ck3.z, dot2bf(qp.w, ck3.w, 0.f))));
        p0 += __shfl_xor(p0, 1, 64);
        p1 += __shfl_xor(p1, 1, 64);
        p2 += __shfl_xor(p2, 1, 64);
        p3 += __shfl_xor(p3, 1, 64);

        float l0 = p0 + sel4(qk0, qk1, qk2, qk3, t0);
        float l1 = p1 + sel4(qk0, qk1, qk2, qk3, t1);
        float l2 = p2 + sel4(qk0, qk1, qk2, qk3, t2);
        float l3 = p3 + sel4(qk0, qk1, qk2, qk3, t3);
        l0 = l0 >= 0.f ? l0 : 0.2f * l0;
        l1 = l1 >= 0.f ? l1 : 0.2f * l1;
        l2 = l2 >= 0.f ? l2 : 0.2f * l2;
        l3 = l3 >= 0.f ? l3 : 0.2f * l3;
        if (n < 2) l1 = -INFINITY;
        if (n < 3) l2 = -INFINITY;
        if (n < 4) l3 = -INFINITY;
        float mb = fmaxf(fmaxf(l0, l1), fmaxf(l2, l3));
        float mn = fmaxf(m, mb);
        float f = __expf(m - mn);
        float a0 = __expf(l0 - mn);
        float a1 = __expf(l1 - mn);
        float a2 = __expf(l2 - mn);
        float a3 = __expf(l3 - mn);
        s = s * f + ((a0 + a1) + (a2 + a3));
        f32x2 ff = {f, f};
        acc01 *= ff; acc23 *= ff; acc45 *= ff; acc67 *= ff;
        f32x2 aa0 = {a0, a0}, aa1 = {a1, a1}, aa2 = {a2, a2}, aa3 = {a3, a3};
        acc01 = fma2(aa0, unpk(cw0.x) + (f32x2){va0.x, va0.y}, acc01);
        acc23 = fma2(aa0, unpk(cw0.y) + (f32x2){va0.z, va0.w}, acc23);
        acc45 = fma2(aa0, unpk(cw0.z) + (f32x2){vb0.x, vb0.y}, acc45);
        acc67 = fma2(aa0, unpk(cw0.w) + (f32x2){vb0.z, vb0.w}, acc67);
        acc01 = fma2(aa1, unpk(cw1.x) + (f32x2){va1.x, va1.y}, acc01);
        acc23 = fma2(aa1, unpk(cw1.y) + (f32x2){va1.z, va1.w}, acc23);
        acc45 = fma2(aa1, unpk(cw1.z) + (f32x2){vb1.x, vb1.y}, acc45);
        acc67 = fma2(aa1, unpk(cw1.w) + (f32x2){vb1.z, vb1.w}, acc67);
        acc01 = fma2(aa2, unpk(cw2.x) + (f32x2){va2.x, va2.y}, acc01);
        acc23 = fma2(aa2, unpk(cw2.y) + (f32x2){va2.z, va2.w}, acc23);
        acc45 = fma2(aa2, unpk(cw2.z) + (f32x2){vb2.x, vb2.y}, acc45);
        acc67 = fma2(aa2, unpk(cw2.w) + (f32x2){vb2.z, vb2.w}, acc67);
        acc01 = fma2(aa3, unpk(cw3.x) + (f32x2){va3.x, va3.y}, acc01);
        acc23 = fma2(aa3, unpk(cw3.y) + (f32x2){va3.z, va3.w}, acc23);
        acc45 = fma2(aa3, unpk(cw3.z) + (f32x2){vb3.x, vb3.y}, acc45);
        acc67 = fma2(aa3, unpk(cw3.w) + (f32x2){vb3.z, vb3.w}, acc67);
        m = mn;
      }
      // rotate pipeline
      cp0 = fp0; cp1 = fp1; cp2 = fp2; cp3 = fp3;
      fp0 = gp0; fp1 = gp1; fp2 = gp2; fp3 = gp3;
      ck0 = nk0; ck1 = nk1; ck2 = nk2; ck3 = nk3;
      cw0 = nw0; cw1 = nw1; cw2 = nw2; cw3 = nw3;
      j = jn;
    }
    if (active) {
      float inv = 1.f / (s + 1e-16f);
      float hf = 0.5f * inv;
      uint4 sk = *(const uint4*)(skipb + (size_t)d * D + dim0);
      f32x2 s0 = unpk(sk.x), s1 = unpk(sk.y), s2 = unpk(sk.z), s3 = unpk(sk.w);
      float* op = outp + (size_t)d * D + dim0;
      float4 o0, o1;
      o0.x = 0.5f * s0.x + hf * acc01.x;
      o0.y = 0.5f * s0.y + hf * acc01.y;
      o0.z = 0.5f * s1.x + hf * acc23.x;
      o0.w = 0.5f * s1.y + hf * acc23.y;
      o1.x = 0.5f * s2.x + hf * acc45.x;
      o1.y = 0.5f * s2.y + hf * acc45.y;
      o1.z = 0.5f * s3.x + hf * acc67.x;
      o1.w = 0.5f * s3.y + hf * acc67.y;
      *(float4*)op = o0;
      *(float4*)(op + 4) = o1;
      if (dosum) {
        ls[0] += o0.x; lq[0] += o0.x * o0.x;
        ls[1] += o0.y; lq[1] += o0.y * o0.y;
        ls[2] += o0.z; lq[2] += o0.z * o0.z;
        ls[3] += o0.w; lq[3] += o0.w * o0.w;
        ls[4] += o1.x; lq[4] += o1.x * o1.x;
        ls[5] += o1.y; lq[5] += o1.y * o1.y;
        ls[6] += o1.z; lq[6] += o1.z * o1.z;
        ls[7] += o1.w; lq[7] += o1.w * o1.w;
      }
    }
  }

  if (dosum) {
    // LDS reduce per block, then one global atomic set per block
#pragma unroll
    for (int i = 0; i < 8; ++i) {
      atomicAdd(&bsum[dim0 + i], ls[i]);
      atomicAdd(&bsq[dim0 + i], lq[i]);
    }
    __syncthreads();
    if (threadIdx.x < 128) {
      atomicAdd(&bnsums[threadIdx.x], bsum[threadIdx.x]);
    } else {
      atomicAdd(&bnsums[threadIdx.x], bsq[threadIdx.x - 128]);
    }
  }
}

// ---------- batch norm apply (reduce is fused into attn L0) ----------
__global__ __launch_bounds__(256) void bn_apply(const float* __restrict__ h,
                                                u16* __restrict__ hbf,
                                                const float* __restrict__ sums,
                                                const float* __restrict__ gamma,
                                                const float* __restrict__ beta,
                                                float invN, int total) {
  __shared__ float sc[128], sh[128];
  int tid = threadIdx.x;
  if (tid < 128) {
    float mu = sums[tid] * invN;
    float var = sums[128 + tid] * invN - mu * mu;
    float inv = rsqrtf(var + 1e-5f);
    float s = gamma[tid] * inv;
    sc[tid] = s;
    sh[tid] = beta[tid] - mu * s;
  }
  __syncthreads();
  int i = blockIdx.x * 256 + tid;
  if (i < total) {
    int c = i & 127;
    hbf[i] = f2bf(h[i] * sc[c] + sh[c]);
  }
}

// ---------- launch ----------
extern "C" void kernel_launch(void* const* d_in, const int* in_sizes, int n_in,
                              void* d_out, int out_size, void* d_ws, size_t ws_size,
                              hipStream_t stream) {
  const float* x        = (const float*)d_in[0];
  const int*   ei0      = (const int*)d_in[1];
  const int*   et0      = (const int*)d_in[2];
  const int*   ei1      = (const int*)d_in[3];
  const int*   et1      = (const int*)d_in[4];
  const float* emb_type = (const float*)d_in[5];
  const float* emb_attr = (const float*)d_in[6];
  const float* v2e_Wq   = (const float*)d_in[7];
  const float* v2e_Wk   = (const float*)d_in[8];
  const float* v2e_Wv   = (const float*)d_in[9];
  const float* v2e_We   = (const float*)d_in[10];
  const float* v2e_Wsk  = (const float*)d_in[11];
  const float* e2_Wq    = (const float*)d_in[12];
  const float* e2_Wk    = (const float*)d_in[13];
  const float* e2_Wv    = (const float*)d_in[14];
  const float* e2_We    = (const float*)d_in[15];
  const float* e2_Wsk   = (const float*)d_in[16];
  const float* bn_gamma = (const float*)d_in[17];
  const float* bn_beta  = (const float*)d_in[18];
  float* out = (float*)d_out;

  // workspace layout
  char* wsb = (char*)d_ws;
  size_t off = 0;
  u16* xb  = (u16*)(wsb + off);  off += (size_t)NSRC * D * 2;
  u16* KVb = (u16*)(wsb + off);  off += (size_t)NSRC * D * 2 * 2;  // interleaved K|V
  u16* Qb  = (u16*)(wsb + off);  off += (size_t)NE0 * D * 2;
  u16* Sb  = (u16*)(wsb + off);  off += (size_t)NE0 * D * 2;
  float* hb = (float*)(wsb + off); off += (size_t)NE0 * D * 4;
  u16* hbf = (u16*)(wsb + off);  off += (size_t)NE0 * D * 2;
  u16* wtAll = (u16*)(wsb + off); off += 8 * 16384 * 2;
  int* elist = (int*)(wsb + off);  off += (size_t)ET * 4;
  int* rank  = (int*)(wsb + off);  off += (size_t)ET * 4;
  int* offs  = (int*)(wsb + off);  off += ((size_t)NT + 8) * 4;
  int* bsums = (int*)(wsb + off);  off += 1024;
  float* kv  = (float*)(wsb + off); off += 4 * 512 * 4;
  float* bnsums = (float*)(wsb + off); off += 256 * 4;  // sum[128] | sumsq[128]

  u16* wtK0 = wtAll + 0 * 16384;
  u16* wtV0 = wtAll + 1 * 16384;
  u16* wtQ0 = wtAll + 2 * 16384;
  u16* wtS0 = wtAll + 3 * 16384;
  u16* wtK1 = wtAll + 4 * 16384;
  u16* wtV1 = wtAll + 5 * 16384;
  u16* wtQ1 = wtAll + 6 * 16384;
  u16* wtS1 = wtAll + 7 * 16384;
  float* kep0 = kv;
  float* vep0 = kv + 512;
  float* kep1 = kv + 1024;
  float* vep1 = kv + 1536;

  const int* src0 = ei0;
  const int* dst0 = ei0 + E0N;
  const int* src1 = ei1;
  const int* dst1 = ei1 + E1N;

  // 1: mega-prep (cast + weights + embs + zeroing)
  prep_all<<<BC + 64 + 4 + BZ + 1, 256, 0, stream>>>(
      x, xb, v2e_Wk, v2e_Wv, v2e_Wq, v2e_Wsk, e2_Wk, e2_Wv, e2_Wq, e2_Wsk,
      wtAll, emb_type, emb_attr, v2e_We, e2_We, kv, offs, bnsums);

  // 2-6: CSR for both layers
  csr_count2<<<(ET + 255) / 256, 256, 0, stream>>>(dst0, dst1, offs, rank);
  {
    int nb = (NT + 1023) / 1024;
    scan1<<<nb, 256, 0, stream>>>(offs, offs, bsums, NT);
    scan2<<<1, 256, 0, stream>>>(bsums, nb);
    scan3<<<(NT + 255) / 256, 256, 0, stream>>>(offs, bsums, NT, ET);
  }
  csr_fill2<<<(ET + 255) / 256, 256, 0, stream>>>(dst0, src0, et0, dst1, src1, et1,
                                                  offs, rank, elist);

  // 7-10: layer 0
  {
    int nKV = (NSRC + 127) / 128, nQS = (NE0 + 127) / 128;
    gemm_quad<<<nKV + nQS, 512, 0, stream>>>(xb, wtK0, wtV0, KVb, NSRC, nKV,
                                             wtQ0, wtS0, Qb, Sb, NE0);
  }
  attn_fused<<<ATTN_BLOCKS, 256, 0, stream>>>(elist, offs, Qb, KVb, kep0, vep0,
                                              Sb, hb, NE0, bnsums);
  bn_apply<<<(NE0 * D + 255) / 256, 256, 0, stream>>>(hb, hbf, bnsums, bn_gamma, bn_beta,
                                                      1.0f / (float)NE0, NE0 * D);

  // 11-12: layer 1
  {
    int nKV = (NE0 + 127) / 128, nQS = (NE1 + 127) / 128;
    gemm_quad<<<nKV + nQS, 512, 0, stream>>>(hbf, wtK1, wtV1, KVb, NE0, nKV,
                                             wtQ1, wtS1, Qb, Sb, NE1);
  }
  attn_fused<<<ATTN_BLOCKS, 256, 0, stream>>>(elist, offs + NE0, Qb, KVb, kep1, vep1,
                                              Sb, out, NE1, nullptr);
}

// Round 13
// 570.745 us; speedup vs baseline: 1.4833x; 1.0233x over previous
//
#include <hip/hip_runtime.h>
#include <cstdint>
#include <cstddef>

#define D 128
#define H 8
#define NSRC 200000
#define NE0  100000
#define NE1  50000
#define E0N  1000000
#define E1N  500000
#define NT   (NE0 + NE1)
#define ET   (E0N + E1N)

typedef unsigned short u16;
typedef __attribute__((ext_vector_type(8))) short short8;
typedef __attribute__((ext_vector_type(4))) float f32x4;
typedef __attribute__((ext_vector_type(2))) float f32x2;

// ---------- bf16 helpers ----------
__device__ __forceinline__ u16 f2bf(float f) {
  unsigned u = __float_as_uint(f);
  unsigned r = (u + 0x7fffu + ((u >> 16) & 1u)) >> 16;  // RNE
  return (u16)r;
}
__device__ __forceinline__ float bf2f(u16 u) {
  return __uint_as_float(((unsigned)u) << 16);
}
// unpack 2 packed bf16 (low = even dim) -> f32x2
__device__ __forceinline__ f32x2 unpk(unsigned u) {
  f32x2 r;
  r.x = __uint_as_float(u << 16);
  r.y = __uint_as_float(u & 0xffff0000u);
  return r;
}
// bf16 pair dot with f32 accumulate: d = a.lo*b.lo + a.hi*b.hi + c
__device__ __forceinline__ float dot2bf(unsigned a, unsigned b, float c) {
  float d;
  asm("v_dot2_f32_bf16 %0, %1, %2, %3" : "=v"(d) : "v"(a), "v"(b), "v"(c));
  return d;
}
__device__ __forceinline__ f32x2 fma2(f32x2 a, f32x2 b, f32x2 c) {
  return __builtin_elementwise_fma(a, b, c);
}

// ---------- mega-prep: x cast + weight transpose + emb GEMMs + zero-fill ----------
// block roles: [0,BC) cast | [BC,BC+64) weights | +4 embs | +BZ zero offs | +1 zero bn
#define BC 25000            // (NSRC*D/4)/256
#define BZ 147              // ceil((NT+1)/1024)
static_assert((size_t)BZ * 1024 >= NT + 1, "offs zero-fill must cover NT+1 entries");
__global__ __launch_bounds__(256) void prep_all(
    const float* __restrict__ x, u16* __restrict__ xb,
    const float* w0, const float* w1, const float* w2, const float* w3,
    const float* w4, const float* w5, const float* w6, const float* w7,
    u16* __restrict__ wt,
    const float* __restrict__ embA, const float* __restrict__ embB,
    const float* __restrict__ We0, const float* __restrict__ We1,
    float* __restrict__ kv,
    int* __restrict__ offs, float* __restrict__ bnsums) {
  int b = blockIdx.x;
  if (b < BC) {
    int i = b * 256 + threadIdx.x;
    float4 a = ((const float4*)x)[i];
    ushort4 o;
    o.x = f2bf(a.x); o.y = f2bf(a.y); o.z = f2bf(a.z); o.w = f2bf(a.w);
    ((ushort4*)xb)[i] = o;
  } else if (b < BC + 64) {
    int bb = b - BC;
    const float* wsrc[8] = {w0, w1, w2, w3, w4, w5, w6, w7};
    int mat = bb >> 3;
    int blk = bb & 7;
    const float* W = wsrc[mat];
    // fold 1/sqrt(d)=0.25 into Wq (mats 2 and 6) so Q comes out pre-scaled
    float sc = ((mat & 3) == 2) ? 0.25f : 1.0f;
    u16* out = wt + mat * 16384;
    for (int i = blk * 2048 + threadIdx.x; i < (blk + 1) * 2048; i += 256) {
      int n = i >> 7, k = i & 127;
      out[i] = f2bf(W[k * 128 + n] * sc);
    }
  } else if (b < BC + 68) {
    int bb = b - BC - 64;
    int mat = bb >> 1;
    int t = (bb & 1) * 256 + threadIdx.x;
    const float* We = mat ? We1 : We0;
    float* keOut = kv + mat * 1024;
    float* veOut = keOut + 512;
    int r = t >> 7, c = t & 127;
    float s0 = 0.f, s1 = 0.f;
    for (int k = 0; k < 128; ++k) {
      float w = We[k * 128 + c];
      s0 += embA[r * 128 + k] * w;
      s1 += embB[r * 128 + k] * w;
    }
    keOut[t] = s0;
    veOut[t] = s1;
  } else if (b < BC + 68 + BZ) {
    int base = (b - BC - 68) * 1024 + threadIdx.x * 4;
#pragma unroll
    for (int i = 0; i < 4; ++i)
      if (base + i < NT + 1) offs[base + i] = 0;
  } else {
    bnsums[threadIdx.x] = 0.f;  // 256 floats = bnsum|bnsq
  }
}

// ---------- BN fold (R13): fold batch-norm into L1 weights + bias ----------
// BN(x)_k = s_k x_k + t_k  =>  BN(h)@W = h@(diag(s)W) + bias, bias_n = sum_k t_k W_kn.
// Rescales the 4 L1 weight mats in-place (prep_all regenerates them each launch,
// so graph replay is safe) and emits bias[4][128]. grid=4 (mat), block=128 (n).
__global__ __launch_bounds__(128) void bn_fold(
    u16* __restrict__ wt1, const float* __restrict__ sums,
    const float* __restrict__ gamma, const float* __restrict__ beta,
    float invN, float* __restrict__ bias) {
  __shared__ float s_[128], t_[128];
  int tid = threadIdx.x;
  {
    float mu = sums[tid] * invN;
    float var = sums[128 + tid] * invN - mu * mu;
    float sc = gamma[tid] * rsqrtf(var + 1e-5f);
    s_[tid] = sc;
    t_[tid] = beta[tid] - mu * sc;
  }
  __syncthreads();
  int mat = blockIdx.x, n = tid;
  u16* wrow = wt1 + mat * 16384 + n * 128;
  float b = 0.f;
#pragma unroll 4
  for (int k = 0; k < 128; ++k) {
    float w = bf2f(wrow[k]);
    b += t_[k] * w;
    wrow[k] = f2bf(s_[k] * w);
  }
  bias[mat * 128 + n] = b;
}

// ---------- quad-output MFMA GEMM, weights-in-LDS (R5 design + optional bias) -
__global__ __launch_bounds__(512, 4) void gemm_quad(
    const u16* __restrict__ A,
    const u16* __restrict__ WtK, const u16* __restrict__ WtV,
    u16* __restrict__ CKV, int NA, int nKV,
    const u16* __restrict__ WtQ, const u16* __restrict__ WtS,
    u16* __restrict__ CQ, u16* __restrict__ CS, int NB,
    const float* __restrict__ bias) {
  int bb = blockIdx.x;
  const u16 *Wt0, *Wt1;
  int N, tile0;
  bool ilv = (bb < nKV);
  if (ilv) {
    Wt0 = WtK; Wt1 = WtV; N = NA; tile0 = bb * 128;
  } else {
    Wt0 = WtQ; Wt1 = WtS; N = NB; tile0 = (bb - nKV) * 128;
  }
  int tid = threadIdx.x;
  int w = tid >> 6, lane = tid & 63;
  int g = w >> 1;          // row group: rows [g*32, g*32+32)
  int h = w & 1;           // feature half: features [h*64, h*64+64)
  int lrow = lane & 15, q = lane >> 4;

  __shared__ u16 Wls[2 * 128 * 128];  // 64 KB: both mats, chunk-XOR swizzled

  // 1) issue weight-staging loads FIRST (same 64 KB for all blocks -> L2-hot)
  uint4 wv[8];
#pragma unroll
  for (int i = 0; i < 8; ++i) {
    int m = i * 512 + tid;                       // 4096 x 16B chunks
    const u16* Wsrc = (m >> 11) ? Wt1 : Wt0;
    wv[i] = *(const uint4*)(Wsrc + (size_t)(m & 2047) * 8);
  }

  // 2) issue A-fragment loads (whole K-extent to regs); newer in VMEM FIFO,
  //    so staging's waitcnt leaves them in flight.
  int ra = tile0 + g * 32 + lrow;
  int rb = ra + 16;
  bool oka = ra < N, okb = rb < N;
  const u16* pa = A + (size_t)(oka ? ra : 0) * 128 + q * 8;
  const u16* pb = A + (size_t)(okb ? rb : 0) * 128 + q * 8;
  short8 av[4], bv[4];
#pragma unroll
  for (int kk = 0; kk < 4; ++kk) {
    av[kk] = *(const short8*)(pa + kk * 32);
    bv[kk] = *(const short8*)(pb + kk * 32);
  }

  // 3) LDS write (chunk-XOR swizzle: LDS(row,c) = W(row, c ^ (row&15)))
#pragma unroll
  for (int i = 0; i < 8; ++i) {
    int m = i * 512 + tid;
    int row = (m & 2047) >> 4, c = m & 15;
    *(uint4*)(Wls + (m >> 11) * 16384 + row * 128 + (c ^ (row & 15)) * 8) = wv[i];
  }
  __syncthreads();

  const u16* W0 = Wls + (h * 64) * 128;          // mat0, this wave's half
  const u16* W1 = Wls + 16384 + (h * 64) * 128;  // mat1, this wave's half

  f32x4 acc[2][2][4];  // [mat][rowset][j]
#pragma unroll
  for (int o = 0; o < 2; ++o)
#pragma unroll
    for (int i = 0; i < 2; ++i)
#pragma unroll
      for (int j = 0; j < 4; ++j) acc[o][i][j] = (f32x4){0.f, 0.f, 0.f, 0.f};

  const short8 zero8 = {0, 0, 0, 0, 0, 0, 0, 0};
#pragma unroll
  for (int kk = 0; kk < 4; ++kk) {
    short8 a0 = oka ? av[kk] : zero8;
    short8 a1 = okb ? bv[kk] : zero8;
    int cs = ((kk * 4 + q) ^ lrow) * 8;          // swizzled chunk offset
#pragma unroll
    for (int j = 0; j < 4; ++j) {
      int fr = j * 16 + lrow;                    // (global row &15) == lrow
      short8 b0 = *(const short8*)(W0 + fr * 128 + cs);
      short8 b1 = *(const short8*)(W1 + fr * 128 + cs);
      acc[0][0][j] = __builtin_amdgcn_mfma_f32_16x16x32_bf16(b0, a0, acc[0][0][j], 0, 0, 0);
      acc[0][1][j] = __builtin_amdgcn_mfma_f32_16x16x32_bf16(b0, a1, acc[0][1][j], 0, 0, 0);
      acc[1][0][j] = __builtin_amdgcn_mfma_f32_16x16x32_bf16(b1, a0, acc[1][0][j], 0, 0, 0);
      acc[1][1][j] = __builtin_amdgcn_mfma_f32_16x16x32_bf16(b1, a1, acc[1][1][j], 0, 0, 0);
    }
  }

  // epilogue: lane owns row (tile0 + g*32 + i*16 + lrow);
  // features f = h*64 + j*16 + q*4 + r (4 consecutive per acc quad)
  // bias (L1 only): bias[mat*128 + f], mat = (ilv?0:2)+o
  if (ilv) {
#pragma unroll
    for (int i = 0; i < 2; ++i) {
      int grow = tile0 + g * 32 + i * 16 + lrow;
      if (grow < N) {
#pragma unroll
        for (int o = 0; o < 2; ++o) {
          u16* base = CKV + (size_t)grow * 256 + (o << 3) + ((q & 1) << 2) +
                      ((q >> 1) << 4) + h * 128;
#pragma unroll
          for (int j = 0; j < 4; ++j) {
            f32x4 v = acc[o][i][j];
            float4 bs = {0.f, 0.f, 0.f, 0.f};
            if (bias) bs = *(const float4*)(bias + o * 128 + h * 64 + j * 16 + q * 4);
            ushort4 pk;
            pk.x = f2bf(v[0] + bs.x); pk.y = f2bf(v[1] + bs.y);
            pk.z = f2bf(v[2] + bs.z); pk.w = f2bf(v[3] + bs.w);
            *(ushort4*)(base + j * 32) = pk;
          }
        }
      }
    }
  } else {
#pragma unroll
    for (int o = 0; o < 2; ++o) {
      u16* C = o ? CS : CQ;
#pragma unroll
      for (int i = 0; i < 2; ++i) {
        int grow = tile0 + g * 32 + i * 16 + lrow;
        if (grow < N) {
          u16* base = C + (size_t)grow * 128 + q * 4 + h * 64;
#pragma unroll
          for (int j = 0; j < 4; ++j) {
            f32x4 v = acc[o][i][j];
            float4 bs = {0.f, 0.f, 0.f, 0.f};
            if (bias) bs = *(const float4*)(bias + (2 + o) * 128 + h * 64 + j * 16 + q * 4);
            ushort4 pk;
            pk.x = f2bf(v[0] + bs.x); pk.y = f2bf(v[1] + bs.y);
            pk.z = f2bf(v[2] + bs.z); pk.w = f2bf(v[3] + bs.w);
            *(ushort4*)(base + j * 16) = pk;
          }
        }
      }
    }
  }
}

// ---------- CSR build (both layers, rank-based fill) ----------
__global__ __launch_bounds__(256) void csr_count2(
    const int* __restrict__ dst0, const int* __restrict__ dst1,
    int* __restrict__ cnt, int* __restrict__ rank) {
  int t = blockIdx.x * 256 + threadIdx.x;
  if (t < E0N) {
    rank[t] = atomicAdd(&cnt[dst0[t]], 1);
  } else if (t < ET) {
    rank[t] = atomicAdd(&cnt[NE0 + dst1[t - E0N]], 1);
  }
}

__global__ __launch_bounds__(256) void scan1(const int* __restrict__ cnt,
                                             int* __restrict__ excl,
                                             int* __restrict__ blocksums, int N) {
  __shared__ int sh[256];
  int tid = threadIdx.x;
  int base = blockIdx.x * 1024 + tid * 4;
  int v0 = (base + 0 < N) ? cnt[base + 0] : 0;
  int v1 = (base + 1 < N) ? cnt[base + 1] : 0;
  int v2 = (base + 2 < N) ? cnt[base + 2] : 0;
  int v3 = (base + 3 < N) ? cnt[base + 3] : 0;
  int tsum = v0 + v1 + v2 + v3;
  sh[tid] = tsum;
  __syncthreads();
  for (int off = 1; off < 256; off <<= 1) {
    int t2 = (tid >= off) ? sh[tid - off] : 0;
    __syncthreads();
    sh[tid] += t2;
    __syncthreads();
  }
  int incl = sh[tid];
  if (tid == 255) blocksums[blockIdx.x] = incl;
  int run = incl - tsum;
  if (base + 0 < N) excl[base + 0] = run; run += v0;
  if (base + 1 < N) excl[base + 1] = run; run += v1;
  if (base + 2 < N) excl[base + 2] = run; run += v2;
  if (base + 3 < N) excl[base + 3] = run;
}

__global__ void scan2(int* __restrict__ blocksums, int nb) {
  __shared__ int sh[256];
  int tid = threadIdx.x;
  int v = (tid < nb) ? blocksums[tid] : 0;
  sh[tid] = v;
  __syncthreads();
  for (int off = 1; off < 256; off <<= 1) {
    int t2 = (tid >= off) ? sh[tid - off] : 0;
    __syncthreads();
    sh[tid] += t2;
    __syncthreads();
  }
  if (tid < nb) blocksums[tid] = sh[tid] - v;
}

__global__ __launch_bounds__(256) void scan3(int* __restrict__ offs,
                                             const int* __restrict__ blocksums, int N,
                                             int Etot) {
  int t = blockIdx.x * 256 + threadIdx.x;
  if (t < N) offs[t] += blocksums[t >> 10];
  if (t == 0) offs[N] = Etot;
}

__global__ __launch_bounds__(256) void csr_fill2(
    const int* __restrict__ dst0, const int* __restrict__ src0, const int* __restrict__ et0,
    const int* __restrict__ dst1, const int* __restrict__ src1, const int* __restrict__ et1,
    const int* __restrict__ offs, const int* __restrict__ rank,
    int* __restrict__ elist) {
  int t = blockIdx.x * 256 + threadIdx.x;
  if (t < E0N) {
    int p = offs[dst0[t]] + rank[t];
    elist[p] = (src0[t] << 2) | et0[t];
  } else if (t < ET) {
    int t2 = t - E0N;
    int p = offs[NE0 + dst1[t2]] + rank[t];
    elist[p] = (src1[t2] << 2) | et1[t2];
  }
}

// ---------- fused flash attention + skip combine + optional BN-stats ---------
// R9 body (measured best). outb!=null (L0): write raw-h as bf16 (half the
// write bytes; BN folded into L1 weights by bn_fold); stats accumulated from
// the f32 values pre-rounding. outb==null (L1): write f32 to outp.
__device__ __forceinline__ float sel4(float s0, float s1, float s2, float s3, int ty) {
  float a = (ty & 1) ? s1 : s0;
  float b = (ty & 1) ? s3 : s2;
  return (ty & 2) ? b : a;
}

#define ATTN_BLOCKS 1024

__global__ __launch_bounds__(256) void attn_fused(
    const int* __restrict__ elist, const int* __restrict__ offs,
    const u16* __restrict__ Q, const u16* __restrict__ KV,
    const float* __restrict__ ke, const float* __restrict__ ve,
    const u16* __restrict__ skipb, float* __restrict__ outp,
    u16* __restrict__ outb, int N, float* __restrict__ bnsums) {
  int lane = threadIdx.x & 63;
  int wid = (blockIdx.x << 2) + (threadIdx.x >> 6);   // global wave id
  int wstride = gridDim.x << 2;
  int which = lane >> 4;   // dst slot within wave
  int sub = lane & 15;     // 16 lanes per dst
  int dim0 = sub * 8;      // 8 consecutive dims per lane; head = sub>>1
  int sub16 = sub * 16;    // u16 offset of this lane's group within a KV row
  bool dosum = (bnsums != nullptr);

  // stage ve into LDS once per (persistent) block: [4][136] floats
  __shared__ float vels[4 * 136];
  __shared__ float bsum[128], bsq[128];
  for (int i = threadIdx.x; i < 512; i += 256) {
    int t = i >> 7, c = i & 127;
    vels[t * 136 + c] = ve[t * 128 + c];
  }
  if (threadIdx.x < 128) {
    bsum[threadIdx.x] = 0.f;
    bsq[threadIdx.x] = 0.f;
  }
  __syncthreads();

  float ls[8], lq[8];
#pragma unroll
  for (int i = 0; i < 8; ++i) { ls[i] = 0.f; lq[i] = 0.f; }

  for (int grp = wid; grp * 4 < N; grp += wstride) {
    int d = grp * 4 + which;
    bool active = d < N;
    int dc = active ? d : 0;

    // Q: 8 dims as 4 packed bf16 pairs (already scaled by 1/sqrt(d))
    uint4 qp = *(const uint4*)(Q + (size_t)dc * D + dim0);
    f32x2 u0 = unpk(qp.x), u1 = unpk(qp.y), u2 = unpk(qp.z), u3 = unpk(qp.w);

    // per-type q . (We ek) : reduce over head (2 lanes)
    float qk0, qk1, qk2, qk3;
#pragma unroll
    for (int ty = 0; ty < 4; ++ty) {
      const float* kt = ke + ty * D + dim0;
      float4 ka = *(const float4*)kt;
      float4 kb = *(const float4*)(kt + 4);
      float p = u0.x * ka.x + u0.y * ka.y + u1.x * ka.z + u1.y * ka.w +
                u2.x * kb.x + u2.y * kb.y + u3.x * kb.z + u3.y * kb.w;
      p += __shfl_xor(p, 1, 64);
      if (ty == 0) qk0 = p; else if (ty == 1) qk1 = p; else if (ty == 2) qk2 = p; else qk3 = p;
    }

    int j0 = active ? offs[d] : 0;
    int j1 = active ? offs[d + 1] : 0;
    int j = j0;

    // --- pipeline prologue: codes for j and j+4 ---
    int cp0, cp1, cp2, cp3;      // current
    int fp0, fp1, fp2, fp3;      // future (j+4)
    {
      int i0 = (j + 0 < j1) ? j + 0 : 0;
      int i1 = (j + 1 < j1) ? j + 1 : 0;
      int i2 = (j + 2 < j1) ? j + 2 : 0;
      int i3 = (j + 3 < j1) ? j + 3 : 0;
      cp0 = elist[i0]; cp1 = elist[i1]; cp2 = elist[i2]; cp3 = elist[i3];
      int k0 = (j + 4 < j1) ? j + 4 : 0;
      int k1 = (j + 5 < j1) ? j + 5 : 0;
      int k2 = (j + 6 < j1) ? j + 6 : 0;
      int k3 = (j + 7 < j1) ? j + 7 : 0;
      fp0 = elist[k0]; fp1 = elist[k1]; fp2 = elist[k2]; fp3 = elist[k3];
    }
    // K+V for current batch (one-time exposed latency per group)
    uint4 ck0 = *(const uint4*)(KV + (size_t)(cp0 >> 2) * 256 + sub16);
    uint4 ck1 = *(const uint4*)(KV + (size_t)(cp1 >> 2) * 256 + sub16);
    uint4 ck2 = *(const uint4*)(KV + (size_t)(cp2 >> 2) * 256 + sub16);
    uint4 ck3 = *(const uint4*)(KV + (size_t)(cp3 >> 2) * 256 + sub16);
    uint4 cw0 = *(const uint4*)(KV + (size_t)(cp0 >> 2) * 256 + sub16 + 8);
    uint4 cw1 = *(const uint4*)(KV + (size_t)(cp1 >> 2) * 256 + sub16 + 8);
    uint4 cw2 = *(const uint4*)(KV + (size_t)(cp2 >> 2) * 256 + sub16 + 8);
    uint4 cw3 = *(const uint4*)(KV + (size_t)(cp3 >> 2) * 256 + sub16 + 8);

    float m = -INFINITY, s = 0.f;
    f32x2 acc01 = {0.f, 0.f}, acc23 = {0.f, 0.f}, acc45 = {0.f, 0.f}, acc67 = {0.f, 0.f};

    while (__any(j < j1)) {
      int jn = j + 4;
      // issue K+V for NEXT batch (codes fp* already resident -> no chain)
      uint4 nk0 = *(const uint4*)(KV + (size_t)(fp0 >> 2) * 256 + sub16);
      uint4 nk1 = *(const uint4*)(KV + (size_t)(fp1 >> 2) * 256 + sub16);
      uint4 nk2 = *(const uint4*)(KV + (size_t)(fp2 >> 2) * 256 + sub16);
      uint4 nk3 = *(const uint4*)(KV + (size_t)(fp3 >> 2) * 256 + sub16);
      uint4 nw0 = *(const uint4*)(KV + (size_t)(fp0 >> 2) * 256 + sub16 + 8);
      uint4 nw1 = *(const uint4*)(KV + (size_t)(fp1 >> 2) * 256 + sub16 + 8);
      uint4 nw2 = *(const uint4*)(KV + (size_t)(fp2 >> 2) * 256 + sub16 + 8);
      uint4 nw3 = *(const uint4*)(KV + (size_t)(fp3 >> 2) * 256 + sub16 + 8);
      // load codes for batch j+8 (consumed next iteration)
      int g0 = (jn + 4 < j1) ? jn + 4 : 0;
      int g1 = (jn + 5 < j1) ? jn + 5 : 0;
      int g2 = (jn + 6 < j1) ? jn + 6 : 0;
      int g3 = (jn + 7 < j1) ? jn + 7 : 0;
      int gp0 = elist[g0], gp1 = elist[g1], gp2 = elist[g2], gp3 = elist[g3];

      int n = j1 - j;
      if (n > 0) {
        int t0 = cp0 & 3, t1 = cp1 & 3, t2 = cp2 & 3, t3 = cp3 & 3;
        // type-value rows from LDS (lgkmcnt -- decoupled from gather FIFO)
        const float* vp0 = vels + t0 * 136 + dim0;
        const float* vp1 = vels + t1 * 136 + dim0;
        const float* vp2 = vels + t2 * 136 + dim0;
        const float* vp3 = vels + t3 * 136 + dim0;
        float4 va0 = *(const float4*)vp0, vb0 = *(const float4*)(vp0 + 4);
        float4 va1 = *(const float4*)vp1, vb1 = *(const float4*)(vp1 + 4);
        float4 va2 = *(const float4*)vp2, vb2 = *(const float4*)(vp2 + 4);
        float4 va3 = *(const float4*)vp3, vb3 = *(const float4*)(vp3 + 4);

        // q . k over lane's 8 dims (bf16 dot2), then head-reduce over 2 lanes
        float p0 = dot2bf(qp.x, ck0.x, dot2bf(qp.y, ck0.y, dot2bf(qp.z, ck0.z, dot2bf(qp.w, ck0.w, 0.f))));
        float p1 = dot2bf(qp.x, ck1.x, dot2bf(qp.y, ck1.y, dot2bf(qp.z, ck1.z, dot2bf(qp.w, ck1.w, 0.f))));
        float p2 = dot2bf(qp.x, ck2.x, dot2bf(qp.y, ck2.y, dot2bf(qp.z, ck2.z, dot2bf(qp.w, ck2.w, 0.f))));
        float p3 = dot2bf(qp.x, ck3.x, dot2bf(qp.y, ck3.y, dot2bf(qp.z, ck3.z, dot2bf(qp.w, ck3.w, 0.f))));
        p0 += __shfl_xor(p0, 1, 64);
        p1 += __shfl_xor(p1, 1, 64);
        p2 += __shfl_xor(p2, 1, 64);
        p3 += __shfl_xor(p3, 1, 64);

        float l0 = p0 + sel4(qk0, qk1, qk2, qk3, t0);
        float l1 = p1 + sel4(qk0, qk1, qk2, qk3, t1);
        float l2 = p2 + sel4(qk0, qk1, qk2, qk3, t2);
        float l3 = p3 + sel4(qk0, qk1, qk2, qk3, t3);
        l0 = l0 >= 0.f ? l0 : 0.2f * l0;
        l1 = l1 >= 0.f ? l1 : 0.2f * l1;
        l2 = l2 >= 0.f ? l2 : 0.2f * l2;
        l3 = l3 >= 0.f ? l3 : 0.2f * l3;
        if (n < 2) l1 = -INFINITY;
        if (n < 3) l2 = -INFINITY;
        if (n < 4) l3 = -INFINITY;
        float mb = fmaxf(fmaxf(l0, l1), fmaxf(l2, l3));
        float mn = fmaxf(m, mb);
        float f = __expf(m - mn);
        float a0 = __expf(l0 - mn);
        float a1 = __expf(l1 - mn);
        float a2 = __expf(l2 - mn);
        float a3 = __expf(l3 - mn);
        s = s * f + ((a0 + a1) + (a2 + a3));
        f32x2 ff = {f, f};
        acc01 *= ff; acc23 *= ff; acc45 *= ff; acc67 *= ff;
        f32x2 aa0 = {a0, a0}, aa1 = {a1, a1}, aa2 = {a2, a2}, aa3 = {a3, a3};
        acc01 = fma2(aa0, unpk(cw0.x) + (f32x2){va0.x, va0.y}, acc01);
        acc23 = fma2(aa0, unpk(cw0.y) + (f32x2){va0.z, va0.w}, acc23);
        acc45 = fma2(aa0, unpk(cw0.z) + (f32x2){vb0.x, vb0.y}, acc45);
        acc67 = fma2(aa0, unpk(cw0.w) + (f32x2){vb0.z, vb0.w}, acc67);
        acc01 = fma2(aa1, unpk(cw1.x) + (f32x2){va1.x, va1.y}, acc01);
        acc23 = fma2(aa1, unpk(cw1.y) + (f32x2){va1.z, va1.w}, acc23);
        acc45 = fma2(aa1, unpk(cw1.z) + (f32x2){vb1.x, vb1.y}, acc45);
        acc67 = fma2(aa1, unpk(cw1.w) + (f32x2){vb1.z, vb1.w}, acc67);
        acc01 = fma2(aa2, unpk(cw2.x) + (f32x2){va2.x, va2.y}, acc01);
        acc23 = fma2(aa2, unpk(cw2.y) + (f32x2){va2.z, va2.w}, acc23);
        acc45 = fma2(aa2, unpk(cw2.z) + (f32x2){vb2.x, vb2.y}, acc45);
        acc67 = fma2(aa2, unpk(cw2.w) + (f32x2){vb2.z, vb2.w}, acc67);
        acc01 = fma2(aa3, unpk(cw3.x) + (f32x2){va3.x, va3.y}, acc01);
        acc23 = fma2(aa3, unpk(cw3.y) + (f32x2){va3.z, va3.w}, acc23);
        acc45 = fma2(aa3, unpk(cw3.z) + (f32x2){vb3.x, vb3.y}, acc45);
        acc67 = fma2(aa3, unpk(cw3.w) + (f32x2){vb3.z, vb3.w}, acc67);
        m = mn;
      }
      // rotate pipeline
      cp0 = fp0; cp1 = fp1; cp2 = fp2; cp3 = fp3;
      fp0 = gp0; fp1 = gp1; fp2 = gp2; fp3 = gp3;
      ck0 = nk0; ck1 = nk1; ck2 = nk2; ck3 = nk3;
      cw0 = nw0; cw1 = nw1; cw2 = nw2; cw3 = nw3;
      j = jn;
    }
    if (active) {
      float inv = 1.f / (s + 1e-16f);
      float hf = 0.5f * inv;
      uint4 sk = *(const uint4*)(skipb + (size_t)d * D + dim0);
      f32x2 s0 = unpk(sk.x), s1 = unpk(sk.y), s2 = unpk(sk.z), s3 = unpk(sk.w);
      float4 o0, o1;
      o0.x = 0.5f * s0.x + hf * acc01.x;
      o0.y = 0.5f * s0.y + hf * acc01.y;
      o0.z = 0.5f * s1.x + hf * acc23.x;
      o0.w = 0.5f * s1.y + hf * acc23.y;
      o1.x = 0.5f * s2.x + hf * acc45.x;
      o1.y = 0.5f * s2.y + hf * acc45.y;
      o1.z = 0.5f * s3.x + hf * acc67.x;
      o1.w = 0.5f * s3.y + hf * acc67.y;
      if (outb) {
        ushort4 pA, pB;
        pA.x = f2bf(o0.x); pA.y = f2bf(o0.y); pA.z = f2bf(o0.z); pA.w = f2bf(o0.w);
        pB.x = f2bf(o1.x); pB.y = f2bf(o1.y); pB.z = f2bf(o1.z); pB.w = f2bf(o1.w);
        u16* ob = outb + (size_t)d * D + dim0;
        *(ushort4*)ob = pA;
        *(ushort4*)(ob + 4) = pB;
      } else {
        float* op = outp + (size_t)d * D + dim0;
        *(float4*)op = o0;
        *(float4*)(op + 4) = o1;
      }
      if (dosum) {
        ls[0] += o0.x; lq[0] += o0.x * o0.x;
        ls[1] += o0.y; lq[1] += o0.y * o0.y;
        ls[2] += o0.z; lq[2] += o0.z * o0.z;
        ls[3] += o0.w; lq[3] += o0.w * o0.w;
        ls[4] += o1.x; lq[4] += o1.x * o1.x;
        ls[5] += o1.y; lq[5] += o1.y * o1.y;
        ls[6] += o1.z; lq[6] += o1.z * o1.z;
        ls[7] += o1.w; lq[7] += o1.w * o1.w;
      }
    }
  }

  if (dosum) {
    // LDS reduce per block, then one global atomic set per block
#pragma unroll
    for (int i = 0; i < 8; ++i) {
      atomicAdd(&bsum[dim0 + i], ls[i]);
      atomicAdd(&bsq[dim0 + i], lq[i]);
    }
    __syncthreads();
    if (threadIdx.x < 128) {
      atomicAdd(&bnsums[threadIdx.x], bsum[threadIdx.x]);
    } else {
      atomicAdd(&bnsums[threadIdx.x], bsq[threadIdx.x - 128]);
    }
  }
}

// ---------- launch ----------
extern "C" void kernel_launch(void* const* d_in, const int* in_sizes, int n_in,
                              void* d_out, int out_size, void* d_ws, size_t ws_size,
                              hipStream_t stream) {
  const float* x        = (const float*)d_in[0];
  const int*   ei0      = (const int*)d_in[1];
  const int*   et0      = (const int*)d_in[2];
  const int*   ei1      = (const int*)d_in[3];
  const int*   et1      = (const int*)d_in[4];
  const float* emb_type = (const float*)d_in[5];
  const float* emb_attr = (const float*)d_in[6];
  const float* v2e_Wq   = (const float*)d_in[7];
  const float* v2e_Wk   = (const float*)d_in[8];
  const float* v2e_Wv   = (const float*)d_in[9];
  const float* v2e_We   = (const float*)d_in[10];
  const float* v2e_Wsk  = (const float*)d_in[11];
  const float* e2_Wq    = (const float*)d_in[12];
  const float* e2_Wk    = (const float*)d_in[13];
  const float* e2_Wv    = (const float*)d_in[14];
  const float* e2_We    = (const float*)d_in[15];
  const float* e2_Wsk   = (const float*)d_in[16];
  const float* bn_gamma = (const float*)d_in[17];
  const float* bn_beta  = (const float*)d_in[18];
  float* out = (float*)d_out;

  // workspace layout
  char* wsb = (char*)d_ws;
  size_t off = 0;
  u16* xb  = (u16*)(wsb + off);  off += (size_t)NSRC * D * 2;
  u16* KVb = (u16*)(wsb + off);  off += (size_t)NSRC * D * 2 * 2;  // interleaved K|V
  u16* Qb  = (u16*)(wsb + off);  off += (size_t)NE0 * D * 2;
  u16* Sb  = (u16*)(wsb + off);  off += (size_t)NE0 * D * 2;
  u16* hbf = (u16*)(wsb + off);  off += (size_t)NE0 * D * 2;   // raw h, bf16
  u16* wtAll = (u16*)(wsb + off); off += 8 * 16384 * 2;
  int* elist = (int*)(wsb + off);  off += (size_t)ET * 4;
  int* rank  = (int*)(wsb + off);  off += (size_t)ET * 4;
  int* offs  = (int*)(wsb + off);  off += ((size_t)NT + 8) * 4;
  int* bsums = (int*)(wsb + off);  off += 1024;
  float* kv  = (float*)(wsb + off); off += 4 * 512 * 4;
  float* bnsums = (float*)(wsb + off); off += 256 * 4;  // sum[128] | sumsq[128]
  float* bias = (float*)(wsb + off); off += 512 * 4;    // K|V|Q|S x 128

  u16* wtK0 = wtAll + 0 * 16384;
  u16* wtV0 = wtAll + 1 * 16384;
  u16* wtQ0 = wtAll + 2 * 16384;
  u16* wtS0 = wtAll + 3 * 16384;
  u16* wtK1 = wtAll + 4 * 16384;
  u16* wtV1 = wtAll + 5 * 16384;
  u16* wtQ1 = wtAll + 6 * 16384;
  u16* wtS1 = wtAll + 7 * 16384;
  float* kep0 = kv;
  float* vep0 = kv + 512;
  float* kep1 = kv + 1024;
  float* vep1 = kv + 1536;

  const int* src0 = ei0;
  const int* dst0 = ei0 + E0N;
  const int* src1 = ei1;
  const int* dst1 = ei1 + E1N;

  // 1: mega-prep (cast + weights + embs + zeroing)
  prep_all<<<BC + 64 + 4 + BZ + 1, 256, 0, stream>>>(
      x, xb, v2e_Wk, v2e_Wv, v2e_Wq, v2e_Wsk, e2_Wk, e2_Wv, e2_Wq, e2_Wsk,
      wtAll, emb_type, emb_attr, v2e_We, e2_We, kv, offs, bnsums);

  // 2-6: CSR for both layers
  csr_count2<<<(ET + 255) / 256, 256, 0, stream>>>(dst0, dst1, offs, rank);
  {
    int nb = (NT + 1023) / 1024;
    scan1<<<nb, 256, 0, stream>>>(offs, offs, bsums, NT);
    scan2<<<1, 256, 0, stream>>>(bsums, nb);
    scan3<<<(NT + 255) / 256, 256, 0, stream>>>(offs, bsums, NT, ET);
  }
  csr_fill2<<<(ET + 255) / 256, 256, 0, stream>>>(dst0, src0, et0, dst1, src1, et1,
                                                  offs, rank, elist);

  // 7-9: layer 0 (attn writes raw-h bf16 + BN stats)
  {
    int nKV = (NSRC + 127) / 128, nQS = (NE0 + 127) / 128;
    gemm_quad<<<nKV + nQS, 512, 0, stream>>>(xb, wtK0, wtV0, KVb, NSRC, nKV,
                                             wtQ0, wtS0, Qb, Sb, NE0, nullptr);
  }
  attn_fused<<<ATTN_BLOCKS, 256, 0, stream>>>(elist, offs, Qb, KVb, kep0, vep0,
                                              Sb, nullptr, hbf, NE0, bnsums);

  // 10: fold BN into L1 weights + bias (replaces bn_apply)
  bn_fold<<<4, 128, 0, stream>>>(wtK1, bnsums, bn_gamma, bn_beta,
                                 1.0f / (float)NE0, bias);

  // 11-12: layer 1 (gemm adds BN bias)
  {
    int nKV = (NE0 + 127) / 128, nQS = (NE1 + 127) / 128;
    gemm_quad<<<nKV + nQS, 512, 0, stream>>>(hbf, wtK1, wtV1, KVb, NE0, nKV,
                                             wtQ1, wtS1, Qb, Sb, NE1, bias);
  }
  attn_fused<<<ATTN_BLOCKS, 256, 0, stream>>>(elist, offs + NE0, Qb, KVb, kep1, vep1,
                                              Sb, out, nullptr, NE1, nullptr);
}